// Round 14
// baseline (403.158 us; speedup 1.0000x reference)
//
#include <hip/hip_runtime.h>

#define B_ 32
#define Q_ 128
#define S_ 2048
#define C_ 1024
#define D_ 1024

typedef __attribute__((ext_vector_type(8))) short bf16x8;
typedef __attribute__((ext_vector_type(4))) float f32x4;

static __device__ __forceinline__ unsigned short f2bf(float f) {
  unsigned int u = __float_as_uint(f);
  u = (u + 0x7FFFu + ((u >> 16) & 1u)) >> 16;
  return (unsigned short)u;
}
static __device__ __forceinline__ float bf2f(unsigned short h) {
  return __uint_as_float(((unsigned int)h) << 16);
}

// async 16B global->LDS (DMA; dest = wave-uniform base + lane*16)
static __device__ __forceinline__ void gl_lds16(const float* g, float* l) {
  __builtin_amdgcn_global_load_lds(
      (const __attribute__((address_space(1))) unsigned int*)g,
      (__attribute__((address_space(3))) unsigned int*)l, 16, 0, 0);
}

// split 8 f32 (two f32x4) into hi/lo bf16x8 (rounded hi, rounded residual)
static __device__ __forceinline__ void split8(const f32x4 x0, const f32x4 x1,
                                              bf16x8& hi, bf16x8& lo) {
  float v[8] = {x0[0], x0[1], x0[2], x0[3], x1[0], x1[1], x1[2], x1[3]};
#pragma unroll
  for (int e = 0; e < 8; ++e) {
    const unsigned short h = f2bf(v[e]);
    hi[e] = (short)h;
    lo[e] = (short)f2bf(v[e] - bf2f(h));
  }
}

// ---------------------------------------------------------------------------
// f32-input split GEMM, BK=64, 128x128 tile, global_load_lds staging.
// C[m,n] = sum_k A[m,k]*B[n,k], A/B f32 rows K-contiguous.
// LDS: sA,sB = f32 [128][64] stored as LDS[r][p] = global[r][p ^ (r&7)]
// (16B chunks; source pre-swizzled so the DMA's linear lane map yields the
// swizzled layout; reads apply the same XOR -> 2-way banks, free).
// Fragments are split to bf16 hi/lo in registers; 3-pass MFMA (hh, hl, lh).
// FUSE: write bf16(B-tile) transposed to fuseOut[bz][k][n] (free ctxT).
// ---------------------------------------------------------------------------
template <bool FUSE>
__global__ __launch_bounds__(256, 2)
void gemm_f32(const float* __restrict__ Aip, const float* __restrict__ Bip,
              float* __restrict__ outp, int K,
              long aBatch, long bBatch, long outBatch,
              long aRstride, long bRstride, long outRstride, int remapQB,
              unsigned short* __restrict__ fuseOut, long fuseRstride) {
  extern __shared__ char smem[];
  float* sA = (float*)smem;            // [128][64] f32, swizzled chunks
  float* sB = sA + 128 * 64;

  const int tid = threadIdx.x;
  const int lane = tid & 63;
  const int w = tid >> 6;              // wave 0..3
  const int wr = w >> 1;
  const int wc = w & 1;
  const int m0 = blockIdx.y * 128;
  const int n0 = blockIdx.x * 128;
  const int bz = blockIdx.z;
  const int frow = lane & 15;
  const int cc = lane >> 4;            // K-subchunk 0..3

  const float* Af = Aip + (long)bz * aBatch;
  const float* Bf = Bip + (long)bz * bBatch;

  f32x4 acc[4][4];
#pragma unroll
  for (int i = 0; i < 4; ++i)
#pragma unroll
    for (int j = 0; j < 4; ++j) acc[i][j] = (f32x4){0.f, 0.f, 0.f, 0.f};

  for (int kt = 0; kt < K; kt += 64) {
    // ---- async staging: 8 issues/wave per tile, pre-swizzled source ----
#pragma unroll
    for (int i = 0; i < 8; ++i) {
      const int r = (w * 8 + i) * 4 + (lane >> 4);        // tile row 0..127
      const int csrc = (lane & 15) ^ (r & 7);             // source 16B chunk
      gl_lds16(Af + (long)(m0 + r) * aRstride + kt + csrc * 4,
               sA + (w * 8 + i) * 256);
    }
#pragma unroll
    for (int i = 0; i < 8; ++i) {
      const int r = (w * 8 + i) * 4 + (lane >> 4);
      const int csrc = (lane & 15) ^ (r & 7);
      gl_lds16(Bf + (long)(n0 + r) * bRstride + kt + csrc * 4,
               sB + (w * 8 + i) * 256);
    }
    __syncthreads();  // drains DMA (vmcnt 0) + barrier

#pragma unroll
    for (int kk = 0; kk < 2; ++kk) {
      bf16x8 ah[4], al[4], bh[4], bl[4];
#pragma unroll
      for (int i = 0; i < 4; ++i) {
        const int row = wr * 64 + i * 16 + frow;
        const int ch = kk * 8 + cc * 2;
        const f32x4 a0 = *(const f32x4*)(sA + row * 64 + ((ch ^ (row & 7)) << 2));
        const f32x4 a1 = *(const f32x4*)(sA + row * 64 + (((ch + 1) ^ (row & 7)) << 2));
        split8(a0, a1, ah[i], al[i]);
      }
#pragma unroll
      for (int j = 0; j < 4; ++j) {
        const int row = wc * 64 + j * 16 + frow;
        const int ch = kk * 8 + cc * 2;
        const f32x4 b0 = *(const f32x4*)(sB + row * 64 + ((ch ^ (row & 7)) << 2));
        const f32x4 b1 = *(const f32x4*)(sB + row * 64 + (((ch + 1) ^ (row & 7)) << 2));
        split8(b0, b1, bh[j], bl[j]);
      }
#pragma unroll
      for (int i = 0; i < 4; ++i)
#pragma unroll
        for (int j = 0; j < 4; ++j) {
          acc[i][j] = __builtin_amdgcn_mfma_f32_16x16x32_bf16(ah[i], bh[j], acc[i][j], 0, 0, 0);
          acc[i][j] = __builtin_amdgcn_mfma_f32_16x16x32_bf16(ah[i], bl[j], acc[i][j], 0, 0, 0);
          acc[i][j] = __builtin_amdgcn_mfma_f32_16x16x32_bf16(al[i], bh[j], acc[i][j], 0, 0, 0);
        }
    }

    // ---- fused bf16 transposed write-out of the B tile (ctxT) ----
    // thread: k-col = lane (0..63), n rows wid*32..+31; reads are same-row
    // across the wave -> contiguous permuted 256B -> 2-way banks (free).
    if constexpr (FUSE) {
      const int ch = lane >> 2, sub = lane & 3;
      unsigned short vals[32];
#pragma unroll
      for (int i2 = 0; i2 < 32; ++i2) {
        const int row = w * 32 + i2;
        vals[i2] = f2bf(sB[row * 64 + ((ch ^ (row & 7)) << 2) + sub]);
      }
      unsigned short* dst = fuseOut + ((long)bz * K + kt + lane) * fuseRstride +
                            n0 + w * 32;
#pragma unroll
      for (int j = 0; j < 4; ++j)
        *(bf16x8*)(dst + j * 8) = *(const bf16x8*)(vals + j * 8);
    }
    __syncthreads();
  }

  float* out = outp + (long)bz * outBatch;
#pragma unroll
  for (int i = 0; i < 4; ++i) {
#pragma unroll
    for (int rr = 0; rr < 4; ++rr) {
      const int grow = m0 + wr * 64 + i * 16 + ((lane >> 4) << 2) + rr;
      const long orow = remapQB ? ((long)(grow & 31) * 128 + (grow >> 5)) : (long)grow;
      float* orp = out + orow * outRstride;
#pragma unroll
      for (int j = 0; j < 4; ++j) {
        const int col = n0 + wc * 64 + j * 16 + (lane & 15);
        orp[col] = acc[i][j][rr];
      }
    }
  }
}

// ---------------------------------------------------------------------------
// bf16 copy GEMM (round-11 proven, verbatim): BK=64, reg staging, XOR-16B
// swizzle. Used for the composition GEMM only.
// ---------------------------------------------------------------------------
static __device__ __forceinline__ void stage_copy(unsigned short* dst,
                                                  const unsigned short* base,
                                                  long rstride, int kt, int tid) {
  const int r = tid >> 1;
  const int sc = (tid & 1) << 5;
  const int swz = (r & 7) << 4;
  const unsigned short* s = base + (long)r * rstride + kt + sc;
  char* row = (char*)dst + r * 128;
#pragma unroll
  for (int j = 0; j < 4; ++j)
    *(bf16x8*)(row + ((sc * 2 + j * 16) ^ swz)) = *(const bf16x8*)(s + j * 8);
}

__global__ __launch_bounds__(256, 2)
void gemm_bf16(const unsigned short* __restrict__ Aip, const unsigned short* __restrict__ Bip,
               float* __restrict__ outp, int K,
               long aBatch, long bBatch, long outBatch,
               long aRstride, long bRstride, long outRstride) {
  extern __shared__ char smem[];
  unsigned short* sA = (unsigned short*)smem;   // [128][64]
  unsigned short* sB = sA + 128 * 64;

  const int tid = threadIdx.x;
  const int lane = tid & 63;
  const int wid = tid >> 6;
  const int wr = wid >> 1;
  const int wc = wid & 1;
  const int m0 = blockIdx.y * 128;
  const int n0 = blockIdx.x * 128;
  const int bz = blockIdx.z;
  const int frow = lane & 15;

  f32x4 acc[4][4];
#pragma unroll
  for (int i = 0; i < 4; ++i)
#pragma unroll
    for (int j = 0; j < 4; ++j) acc[i][j] = (f32x4){0.f, 0.f, 0.f, 0.f};

  for (int kt = 0; kt < K; kt += 64) {
    stage_copy(sA, Aip + (long)bz * aBatch + (long)m0 * aRstride, aRstride, kt, tid);
    stage_copy(sB, Bip + (long)bz * bBatch + (long)n0 * bRstride, bRstride, kt, tid);
    __syncthreads();

#pragma unroll
    for (int kk = 0; kk < 2; ++kk) {
      const int kb = kk * 64 + ((lane >> 4) << 4);
      bf16x8 ah[4], bh[4];
#pragma unroll
      for (int i = 0; i < 4; ++i) {
        const int row = wr * 64 + i * 16 + frow;
        ah[i] = *(const bf16x8*)((const char*)sA + row * 128 + (kb ^ ((row & 7) << 4)));
      }
#pragma unroll
      for (int j = 0; j < 4; ++j) {
        const int row = wc * 64 + j * 16 + frow;
        bh[j] = *(const bf16x8*)((const char*)sB + row * 128 + (kb ^ ((row & 7) << 4)));
      }
#pragma unroll
      for (int i = 0; i < 4; ++i)
#pragma unroll
        for (int j = 0; j < 4; ++j)
          acc[i][j] = __builtin_amdgcn_mfma_f32_16x16x32_bf16(ah[i], bh[j], acc[i][j], 0, 0, 0);
    }
    __syncthreads();
  }

  float* out = outp + (long)bz * outBatch;
#pragma unroll
  for (int i = 0; i < 4; ++i) {
#pragma unroll
    for (int rr = 0; rr < 4; ++rr) {
      const int grow = m0 + wr * 64 + i * 16 + ((lane >> 4) << 2) + rr;
      float* orp = out + (long)grow * outRstride;
#pragma unroll
      for (int j = 0; j < 4; ++j) {
        const int col = n0 + wc * 64 + j * 16 + (lane & 15);
        orp[col] = acc[i][j][rr];
      }
    }
  }
}

// ---------------------------------------------------------------------------
// Scan (round-9/11 proven, verbatim): 512 threads/block, 4 cols/thread.
// asm prefetch depth 2 + counted vmcnt (3 VMEM/row -> ladder 1/3/5); one raw
// s_barrier per row; parity double-buffered LDS (m,s); exact wave max.
// ---------------------------------------------------------------------------
template <int VM>
static __device__ __forceinline__ void scan_row(
    float* __restrict__ attn, unsigned short* __restrict__ attnb,
    int b, int q, int lane, int wid, int s0,
    const bool* msk, float* acc, f32x4& buf, float2 (&red)[2][8]) {
  const float L2E = 1.4426950408889634f;

  if constexpr (VM == 1)      asm volatile("s_waitcnt vmcnt(1)" ::: "memory");
  else if constexpr (VM == 3) asm volatile("s_waitcnt vmcnt(3)" ::: "memory");
  else                        asm volatile("s_waitcnt vmcnt(5)" ::: "memory");
  __builtin_amdgcn_sched_barrier(0);

  float adj[4];
#pragma unroll
  for (int j = 0; j < 4; ++j)
    adj[j] = msk[j] ? -1e30f : (buf[j] - acc[j]);

  int pr = q + 2; if (pr > Q_ - 1) pr = Q_ - 1;
  const float* pp = attn + ((long)(pr * B_ + b)) * S_ + s0;
  asm volatile("global_load_dwordx4 %0, %1, off"
               : "=&v"(buf)
               : "v"(pp), "v"(adj[0]), "v"(adj[1]), "v"(adj[2]), "v"(adj[3])
               : "memory");

  float lm = fmaxf(fmaxf(adj[0], adj[1]), fmaxf(adj[2], adj[3]));
#pragma unroll
  for (int off = 32; off > 0; off >>= 1) lm = fmaxf(lm, __shfl_xor(lm, off));

  float e[4];
#pragma unroll
  for (int j = 0; j < 4; ++j) {
    const float x = exp2f((adj[j] - lm) * L2E);
    e[j] = msk[j] ? 0.f : x;
  }

  float ls = (e[0] + e[1]) + (e[2] + e[3]);
#pragma unroll
  for (int off = 32; off > 0; off >>= 1) ls += __shfl_xor(ls, off);

  const int p = q & 1;
  if (lane == 0) red[p][wid] = make_float2(lm, ls);
  asm volatile("s_waitcnt lgkmcnt(0)\n\ts_barrier" ::: "memory");

  const float2 v0 = red[p][0], v1 = red[p][1], v2 = red[p][2], v3 = red[p][3];
  const float2 v4 = red[p][4], v5 = red[p][5], v6 = red[p][6], v7 = red[p][7];
  const float M = fmaxf(fmaxf(fmaxf(v0.x, v1.x), fmaxf(v2.x, v3.x)),
                        fmaxf(fmaxf(v4.x, v5.x), fmaxf(v6.x, v7.x)));
  const float tot = v0.y * exp2f((v0.x - M) * L2E) + v1.y * exp2f((v1.x - M) * L2E) +
                    v2.y * exp2f((v2.x - M) * L2E) + v3.y * exp2f((v3.x - M) * L2E) +
                    v4.y * exp2f((v4.x - M) * L2E) + v5.y * exp2f((v5.x - M) * L2E) +
                    v6.y * exp2f((v6.x - M) * L2E) + v7.y * exp2f((v7.x - M) * L2E);
  const float scale = exp2f((lm - M) * L2E) / tot;

  f32x4 av;
#pragma unroll
  for (int j = 0; j < 4; ++j) {
    av[j] = e[j] * scale;
    acc[j] += av[j];
  }
  *(f32x4*)(attn + ((long)(q * B_ + b)) * S_ + s0) = av;
  uint2 pk;
  pk.x = (unsigned int)f2bf(av[0]) | ((unsigned int)f2bf(av[1]) << 16);
  pk.y = (unsigned int)f2bf(av[2]) | ((unsigned int)f2bf(av[3]) << 16);
  *(uint2*)(attnb + ((long)b * Q_ + q) * S_ + s0) = pk;
}

__global__ __launch_bounds__(512)
void scan_kernel(const int* __restrict__ mask, float* __restrict__ attn,
                 float* __restrict__ accum_out, unsigned short* __restrict__ attnb) {
  const int b = blockIdx.x;
  const int tid = threadIdx.x;
  const int lane = tid & 63;
  const int wid = tid >> 6;
  const int s0 = tid * 4;

  __shared__ float2 red[2][8];

  const int4 mk = *(const int4*)(mask + (long)b * S_ + s0);
  const bool msk[4] = {mk.x != 0, mk.y != 0, mk.z != 0, mk.w != 0};
  asm volatile("" :: "v"(mk.x), "v"(mk.y), "v"(mk.z), "v"(mk.w));

  float acc[4] = {0.f, 0.f, 0.f, 0.f};

  f32x4 bufE, bufO;
  const float* p0 = attn + (long)b * S_ + s0;
  asm volatile("global_load_dwordx4 %0, %1, off" : "=&v"(bufE) : "v"(p0) : "memory");
  const float* p1 = attn + ((long)(B_ + b)) * S_ + s0;
  asm volatile("global_load_dwordx4 %0, %1, off" : "=&v"(bufO) : "v"(p1) : "memory");

  scan_row<1>(attn, attnb, b, 0, lane, wid, s0, msk, acc, bufE, red);
  scan_row<3>(attn, attnb, b, 1, lane, wid, s0, msk, acc, bufO, red);
  for (int q = 2; q < Q_; q += 2) {
    scan_row<5>(attn, attnb, b, q,     lane, wid, s0, msk, acc, bufE, red);
    scan_row<5>(attn, attnb, b, q + 1, lane, wid, s0, msk, acc, bufO, red);
  }

  f32x4 a4;
#pragma unroll
  for (int j = 0; j < 4; ++j) a4[j] = acc[j];
  *(f32x4*)(accum_out + (long)b * S_ + s0) = a4;
}

extern "C" void kernel_launch(void* const* d_in, const int* in_sizes, int n_in,
                              void* d_out, int out_size, void* d_ws, size_t ws_size,
                              hipStream_t stream) {
  const float* ctx   = (const float*)d_in[0];  // [B,S,C] f32
  const float* query = (const float*)d_in[1];  // [Q,B,D] f32
  const int*   mask  = (const int*)d_in[2];    // [B,S] int32 (bool)
  const float* W     = (const float*)d_in[3];  // [C,D] f32

  float* out = (float*)d_out;
  float* attn = out;                                      // [Q,B,S]
  float* accum_out = out + (size_t)Q_ * B_ * S_;          // [B,1,S]
  float* comp = accum_out + (size_t)B_ * S_;              // [Q,B,C]

  char* ws = (char*)d_ws;
  float* qw = (float*)ws;                                                   // [B,Q,C] f32, 16 MiB
  unsigned short* ctxT  = (unsigned short*)(ws + (size_t)16 * 1024 * 1024); // [B,C,S] bf16, 128 MiB
  unsigned short* attnb = (unsigned short*)(ws + (size_t)16 * 1024 * 1024 +
                                            (size_t)B_ * C_ * S_ * 2);      // [B,Q,S] bf16, 16 MiB

  // 1) QW[b,q,c] = sum_d query[q,b,d] * W[c,d]  (3-pass split, DMA staging)
  gemm_f32<false><<<dim3(C_ / 128, (Q_ * B_) / 128, 1), 256, 65536, stream>>>(
      query, W, qw, D_, 0L, 0L, 0L, (long)D_, (long)D_, (long)C_, 1, nullptr, 0L);

  // 2) scores[q,b,s] = sum_c QW[b,q,c] * ctx[b,s,c]  + fused ctxT write-out
  gemm_f32<true><<<dim3(S_ / 128, 1, B_), 256, 65536, stream>>>(
      qw, ctx, attn, C_, (long)Q_ * C_, (long)S_ * C_, (long)S_,
      (long)C_, (long)C_, (long)B_ * S_, 0, ctxT, (long)S_);

  // 3) sequential coverage-softmax scan (in-place attention + accum + bf16 copy)
  scan_kernel<<<B_, 512, 0, stream>>>(mask, attn, accum_out, attnb);

  // 4) composition[q,b,c] = sum_s attnb[b,q,s] * ctxT[b,c,s]
  gemm_bf16<<<dim3(C_ / 128, 1, B_), 256, 32768, stream>>>(
      attnb, ctxT, comp, S_, (long)Q_ * S_, (long)C_ * S_, (long)C_,
      (long)S_, (long)S_, (long)B_ * C_);
}

// Round 15
// 402.866 us; speedup vs baseline: 1.0007x; 1.0007x over previous
//
#include <hip/hip_runtime.h>

#define B_ 32
#define Q_ 128
#define S_ 2048
#define C_ 1024
#define D_ 1024

typedef __attribute__((ext_vector_type(8))) short bf16x8;
typedef __attribute__((ext_vector_type(4))) float f32x4;

static __device__ __forceinline__ unsigned short f2bf(float f) {
  unsigned int u = __float_as_uint(f);
  u = (u + 0x7FFFu + ((u >> 16) & 1u)) >> 16;
  return (unsigned short)u;
}
static __device__ __forceinline__ float bf2f(unsigned short h) {
  return __uint_as_float(((unsigned int)h) << 16);
}

// async 16B global->LDS (DMA; dest = wave-uniform base + lane*16)
static __device__ __forceinline__ void gl_lds16(const float* g, float* l) {
  __builtin_amdgcn_global_load_lds(
      (const __attribute__((address_space(1))) unsigned int*)g,
      (__attribute__((address_space(3))) unsigned int*)l, 16, 0, 0);
}

// split 8 f32 (two f32x4) into hi/lo bf16x8 (rounded hi, rounded residual)
static __device__ __forceinline__ void split8(const f32x4 x0, const f32x4 x1,
                                              bf16x8& hi, bf16x8& lo) {
  float v[8] = {x0[0], x0[1], x0[2], x0[3], x1[0], x1[1], x1[2], x1[3]};
#pragma unroll
  for (int e = 0; e < 8; ++e) {
    const unsigned short h = f2bf(v[e]);
    hi[e] = (short)h;
    lo[e] = (short)f2bf(v[e] - bf2f(h));
  }
}

// ---------------------------------------------------------------------------
// f32-input split GEMM, BK=64, 128x128 tile, global_load_lds staging.
// C[m,n] = sum_k A[m,k]*B[n,k], A/B f32 rows K-contiguous.
// LDS: sA,sB = f32 [128][64] stored as LDS[r][p] = global[r][p ^ (r&7)]
// (16B chunks; source pre-swizzled so the DMA's linear lane map yields the
// swizzled layout; reads apply the same XOR -> 2-way banks, free).
// Fragments are split to bf16 hi/lo in registers; 3-pass MFMA (hh, hl, lh).
// FUSE: write bf16(B-tile) transposed to fuseOut[bz][k][n] (free ctxT).
// ---------------------------------------------------------------------------
template <bool FUSE>
__global__ __launch_bounds__(256, 2)
void gemm_f32(const float* __restrict__ Aip, const float* __restrict__ Bip,
              float* __restrict__ outp, int K,
              long aBatch, long bBatch, long outBatch,
              long aRstride, long bRstride, long outRstride, int remapQB,
              unsigned short* __restrict__ fuseOut, long fuseRstride) {
  extern __shared__ char smem[];
  float* sA = (float*)smem;            // [128][64] f32, swizzled chunks
  float* sB = sA + 128 * 64;

  const int tid = threadIdx.x;
  const int lane = tid & 63;
  const int w = tid >> 6;              // wave 0..3
  const int wr = w >> 1;
  const int wc = w & 1;
  const int m0 = blockIdx.y * 128;
  const int n0 = blockIdx.x * 128;
  const int bz = blockIdx.z;
  const int frow = lane & 15;
  const int cc = lane >> 4;            // K-subchunk 0..3

  const float* Af = Aip + (long)bz * aBatch;
  const float* Bf = Bip + (long)bz * bBatch;

  f32x4 acc[4][4];
#pragma unroll
  for (int i = 0; i < 4; ++i)
#pragma unroll
    for (int j = 0; j < 4; ++j) acc[i][j] = (f32x4){0.f, 0.f, 0.f, 0.f};

  for (int kt = 0; kt < K; kt += 64) {
    // ---- async staging: 8 issues/wave per tile, pre-swizzled source ----
#pragma unroll
    for (int i = 0; i < 8; ++i) {
      const int r = (w * 8 + i) * 4 + (lane >> 4);        // tile row 0..127
      const int csrc = (lane & 15) ^ (r & 7);             // source 16B chunk
      gl_lds16(Af + (long)(m0 + r) * aRstride + kt + csrc * 4,
               sA + (w * 8 + i) * 256);
    }
#pragma unroll
    for (int i = 0; i < 8; ++i) {
      const int r = (w * 8 + i) * 4 + (lane >> 4);
      const int csrc = (lane & 15) ^ (r & 7);
      gl_lds16(Bf + (long)(n0 + r) * bRstride + kt + csrc * 4,
               sB + (w * 8 + i) * 256);
    }
    __syncthreads();  // drains DMA (vmcnt 0) + barrier

#pragma unroll
    for (int kk = 0; kk < 2; ++kk) {
      bf16x8 ah[4], al[4], bh[4], bl[4];
#pragma unroll
      for (int i = 0; i < 4; ++i) {
        const int row = wr * 64 + i * 16 + frow;
        const int ch = kk * 8 + cc * 2;
        const f32x4 a0 = *(const f32x4*)(sA + row * 64 + ((ch ^ (row & 7)) << 2));
        const f32x4 a1 = *(const f32x4*)(sA + row * 64 + (((ch + 1) ^ (row & 7)) << 2));
        split8(a0, a1, ah[i], al[i]);
      }
#pragma unroll
      for (int j = 0; j < 4; ++j) {
        const int row = wc * 64 + j * 16 + frow;
        const int ch = kk * 8 + cc * 2;
        const f32x4 b0 = *(const f32x4*)(sB + row * 64 + ((ch ^ (row & 7)) << 2));
        const f32x4 b1 = *(const f32x4*)(sB + row * 64 + (((ch + 1) ^ (row & 7)) << 2));
        split8(b0, b1, bh[j], bl[j]);
      }
#pragma unroll
      for (int i = 0; i < 4; ++i)
#pragma unroll
        for (int j = 0; j < 4; ++j) {
          acc[i][j] = __builtin_amdgcn_mfma_f32_16x16x32_bf16(ah[i], bh[j], acc[i][j], 0, 0, 0);
          acc[i][j] = __builtin_amdgcn_mfma_f32_16x16x32_bf16(ah[i], bl[j], acc[i][j], 0, 0, 0);
          acc[i][j] = __builtin_amdgcn_mfma_f32_16x16x32_bf16(al[i], bh[j], acc[i][j], 0, 0, 0);
        }
    }

    // ---- fused bf16 transposed write-out of the B tile (ctxT) ----
    // thread: k-col = lane (0..63), n rows wid*32..+31; reads are same-row
    // across the wave -> contiguous permuted 256B -> 2-way banks (free).
    if constexpr (FUSE) {
      const int ch = lane >> 2, sub = lane & 3;
      unsigned short vals[32];
#pragma unroll
      for (int i2 = 0; i2 < 32; ++i2) {
        const int row = w * 32 + i2;
        vals[i2] = f2bf(sB[row * 64 + ((ch ^ (row & 7)) << 2) + sub]);
      }
      unsigned short* dst = fuseOut + ((long)bz * K + kt + lane) * fuseRstride +
                            n0 + w * 32;
#pragma unroll
      for (int j = 0; j < 4; ++j)
        *(bf16x8*)(dst + j * 8) = *(const bf16x8*)(vals + j * 8);
    }
    __syncthreads();
  }

  float* out = outp + (long)bz * outBatch;
#pragma unroll
  for (int i = 0; i < 4; ++i) {
#pragma unroll
    for (int rr = 0; rr < 4; ++rr) {
      const int grow = m0 + wr * 64 + i * 16 + ((lane >> 4) << 2) + rr;
      const long orow = remapQB ? ((long)(grow & 31) * 128 + (grow >> 5)) : (long)grow;
      float* orp = out + orow * outRstride;
#pragma unroll
      for (int j = 0; j < 4; ++j) {
        const int col = n0 + wc * 64 + j * 16 + (lane & 15);
        orp[col] = acc[i][j][rr];
      }
    }
  }
}

// ---------------------------------------------------------------------------
// bf16 copy GEMM (round-11 proven, verbatim): BK=64, reg staging, XOR-16B
// swizzle. Used for the composition GEMM only.
// ---------------------------------------------------------------------------
static __device__ __forceinline__ void stage_copy(unsigned short* dst,
                                                  const unsigned short* base,
                                                  long rstride, int kt, int tid) {
  const int r = tid >> 1;
  const int sc = (tid & 1) << 5;
  const int swz = (r & 7) << 4;
  const unsigned short* s = base + (long)r * rstride + kt + sc;
  char* row = (char*)dst + r * 128;
#pragma unroll
  for (int j = 0; j < 4; ++j)
    *(bf16x8*)(row + ((sc * 2 + j * 16) ^ swz)) = *(const bf16x8*)(s + j * 8);
}

__global__ __launch_bounds__(256, 2)
void gemm_bf16(const unsigned short* __restrict__ Aip, const unsigned short* __restrict__ Bip,
               float* __restrict__ outp, int K,
               long aBatch, long bBatch, long outBatch,
               long aRstride, long bRstride, long outRstride) {
  extern __shared__ char smem[];
  unsigned short* sA = (unsigned short*)smem;   // [128][64]
  unsigned short* sB = sA + 128 * 64;

  const int tid = threadIdx.x;
  const int lane = tid & 63;
  const int wid = tid >> 6;
  const int wr = wid >> 1;
  const int wc = wid & 1;
  const int m0 = blockIdx.y * 128;
  const int n0 = blockIdx.x * 128;
  const int bz = blockIdx.z;
  const int frow = lane & 15;

  f32x4 acc[4][4];
#pragma unroll
  for (int i = 0; i < 4; ++i)
#pragma unroll
    for (int j = 0; j < 4; ++j) acc[i][j] = (f32x4){0.f, 0.f, 0.f, 0.f};

  for (int kt = 0; kt < K; kt += 64) {
    stage_copy(sA, Aip + (long)bz * aBatch + (long)m0 * aRstride, aRstride, kt, tid);
    stage_copy(sB, Bip + (long)bz * bBatch + (long)n0 * bRstride, bRstride, kt, tid);
    __syncthreads();

#pragma unroll
    for (int kk = 0; kk < 2; ++kk) {
      const int kb = kk * 64 + ((lane >> 4) << 4);
      bf16x8 ah[4], bh[4];
#pragma unroll
      for (int i = 0; i < 4; ++i) {
        const int row = wr * 64 + i * 16 + frow;
        ah[i] = *(const bf16x8*)((const char*)sA + row * 128 + (kb ^ ((row & 7) << 4)));
      }
#pragma unroll
      for (int j = 0; j < 4; ++j) {
        const int row = wc * 64 + j * 16 + frow;
        bh[j] = *(const bf16x8*)((const char*)sB + row * 128 + (kb ^ ((row & 7) << 4)));
      }
#pragma unroll
      for (int i = 0; i < 4; ++i)
#pragma unroll
        for (int j = 0; j < 4; ++j)
          acc[i][j] = __builtin_amdgcn_mfma_f32_16x16x32_bf16(ah[i], bh[j], acc[i][j], 0, 0, 0);
    }
    __syncthreads();
  }

  float* out = outp + (long)bz * outBatch;
#pragma unroll
  for (int i = 0; i < 4; ++i) {
#pragma unroll
    for (int rr = 0; rr < 4; ++rr) {
      const int grow = m0 + wr * 64 + i * 16 + ((lane >> 4) << 2) + rr;
      float* orp = out + (long)grow * outRstride;
#pragma unroll
      for (int j = 0; j < 4; ++j) {
        const int col = n0 + wc * 64 + j * 16 + (lane & 15);
        orp[col] = acc[i][j][rr];
      }
    }
  }
}

// ---------------------------------------------------------------------------
// Scan (round-9/11 proven, verbatim): 512 threads/block, 4 cols/thread.
// asm prefetch depth 2 + counted vmcnt (3 VMEM/row -> ladder 1/3/5); one raw
// s_barrier per row; parity double-buffered LDS (m,s); exact wave max.
// ---------------------------------------------------------------------------
template <int VM>
static __device__ __forceinline__ void scan_row(
    float* __restrict__ attn, unsigned short* __restrict__ attnb,
    int b, int q, int lane, int wid, int s0,
    const bool* msk, float* acc, f32x4& buf, float2 (&red)[2][8]) {
  const float L2E = 1.4426950408889634f;

  if constexpr (VM == 1)      asm volatile("s_waitcnt vmcnt(1)" ::: "memory");
  else if constexpr (VM == 3) asm volatile("s_waitcnt vmcnt(3)" ::: "memory");
  else                        asm volatile("s_waitcnt vmcnt(5)" ::: "memory");
  __builtin_amdgcn_sched_barrier(0);

  float adj[4];
#pragma unroll
  for (int j = 0; j < 4; ++j)
    adj[j] = msk[j] ? -1e30f : (buf[j] - acc[j]);

  int pr = q + 2; if (pr > Q_ - 1) pr = Q_ - 1;
  const float* pp = attn + ((long)(pr * B_ + b)) * S_ + s0;
  asm volatile("global_load_dwordx4 %0, %1, off"
               : "=&v"(buf)
               : "v"(pp), "v"(adj[0]), "v"(adj[1]), "v"(adj[2]), "v"(adj[3])
               : "memory");

  float lm = fmaxf(fmaxf(adj[0], adj[1]), fmaxf(adj[2], adj[3]));
#pragma unroll
  for (int off = 32; off > 0; off >>= 1) lm = fmaxf(lm, __shfl_xor(lm, off));

  float e[4];
#pragma unroll
  for (int j = 0; j < 4; ++j) {
    const float x = exp2f((adj[j] - lm) * L2E);
    e[j] = msk[j] ? 0.f : x;
  }

  float ls = (e[0] + e[1]) + (e[2] + e[3]);
#pragma unroll
  for (int off = 32; off > 0; off >>= 1) ls += __shfl_xor(ls, off);

  const int p = q & 1;
  if (lane == 0) red[p][wid] = make_float2(lm, ls);
  asm volatile("s_waitcnt lgkmcnt(0)\n\ts_barrier" ::: "memory");

  const float2 v0 = red[p][0], v1 = red[p][1], v2 = red[p][2], v3 = red[p][3];
  const float2 v4 = red[p][4], v5 = red[p][5], v6 = red[p][6], v7 = red[p][7];
  const float M = fmaxf(fmaxf(fmaxf(v0.x, v1.x), fmaxf(v2.x, v3.x)),
                        fmaxf(fmaxf(v4.x, v5.x), fmaxf(v6.x, v7.x)));
  const float tot = v0.y * exp2f((v0.x - M) * L2E) + v1.y * exp2f((v1.x - M) * L2E) +
                    v2.y * exp2f((v2.x - M) * L2E) + v3.y * exp2f((v3.x - M) * L2E) +
                    v4.y * exp2f((v4.x - M) * L2E) + v5.y * exp2f((v5.x - M) * L2E) +
                    v6.y * exp2f((v6.x - M) * L2E) + v7.y * exp2f((v7.x - M) * L2E);
  const float scale = exp2f((lm - M) * L2E) / tot;

  f32x4 av;
#pragma unroll
  for (int j = 0; j < 4; ++j) {
    av[j] = e[j] * scale;
    acc[j] += av[j];
  }
  *(f32x4*)(attn + ((long)(q * B_ + b)) * S_ + s0) = av;
  uint2 pk;
  pk.x = (unsigned int)f2bf(av[0]) | ((unsigned int)f2bf(av[1]) << 16);
  pk.y = (unsigned int)f2bf(av[2]) | ((unsigned int)f2bf(av[3]) << 16);
  *(uint2*)(attnb + ((long)b * Q_ + q) * S_ + s0) = pk;
}

__global__ __launch_bounds__(512)
void scan_kernel(const int* __restrict__ mask, float* __restrict__ attn,
                 float* __restrict__ accum_out, unsigned short* __restrict__ attnb) {
  const int b = blockIdx.x;
  const int tid = threadIdx.x;
  const int lane = tid & 63;
  const int wid = tid >> 6;
  const int s0 = tid * 4;

  __shared__ float2 red[2][8];

  const int4 mk = *(const int4*)(mask + (long)b * S_ + s0);
  const bool msk[4] = {mk.x != 0, mk.y != 0, mk.z != 0, mk.w != 0};
  asm volatile("" :: "v"(mk.x), "v"(mk.y), "v"(mk.z), "v"(mk.w));

  float acc[4] = {0.f, 0.f, 0.f, 0.f};

  f32x4 bufE, bufO;
  const float* p0 = attn + (long)b * S_ + s0;
  asm volatile("global_load_dwordx4 %0, %1, off" : "=&v"(bufE) : "v"(p0) : "memory");
  const float* p1 = attn + ((long)(B_ + b)) * S_ + s0;
  asm volatile("global_load_dwordx4 %0, %1, off" : "=&v"(bufO) : "v"(p1) : "memory");

  scan_row<1>(attn, attnb, b, 0, lane, wid, s0, msk, acc, bufE, red);
  scan_row<3>(attn, attnb, b, 1, lane, wid, s0, msk, acc, bufO, red);
  for (int q = 2; q < Q_; q += 2) {
    scan_row<5>(attn, attnb, b, q,     lane, wid, s0, msk, acc, bufE, red);
    scan_row<5>(attn, attnb, b, q + 1, lane, wid, s0, msk, acc, bufO, red);
  }

  f32x4 a4;
#pragma unroll
  for (int j = 0; j < 4; ++j) a4[j] = acc[j];
  *(f32x4*)(accum_out + (long)b * S_ + s0) = a4;
}

extern "C" void kernel_launch(void* const* d_in, const int* in_sizes, int n_in,
                              void* d_out, int out_size, void* d_ws, size_t ws_size,
                              hipStream_t stream) {
  const float* ctx   = (const float*)d_in[0];  // [B,S,C] f32
  const float* query = (const float*)d_in[1];  // [Q,B,D] f32
  const int*   mask  = (const int*)d_in[2];    // [B,S] int32 (bool)
  const float* W     = (const float*)d_in[3];  // [C,D] f32

  float* out = (float*)d_out;
  float* attn = out;                                      // [Q,B,S]
  float* accum_out = out + (size_t)Q_ * B_ * S_;          // [B,1,S]
  float* comp = accum_out + (size_t)B_ * S_;              // [Q,B,C]

  char* ws = (char*)d_ws;
  float* qw = (float*)ws;                                                   // [B,Q,C] f32, 16 MiB
  unsigned short* ctxT  = (unsigned short*)(ws + (size_t)16 * 1024 * 1024); // [B,C,S] bf16, 128 MiB
  unsigned short* attnb = (unsigned short*)(ws + (size_t)16 * 1024 * 1024 +
                                            (size_t)B_ * C_ * S_ * 2);      // [B,Q,S] bf16, 16 MiB

  // 1) QW[b,q,c] = sum_d query[q,b,d] * W[c,d]  (3-pass split, DMA staging)
  gemm_f32<false><<<dim3(C_ / 128, (Q_ * B_) / 128, 1), 256, 65536, stream>>>(
      query, W, qw, D_, 0L, 0L, 0L, (long)D_, (long)D_, (long)C_, 1, nullptr, 0L);

  // 2) scores[q,b,s] = sum_c QW[b,q,c] * ctx[b,s,c]  + fused ctxT write-out
  gemm_f32<true><<<dim3(S_ / 128, 1, B_), 256, 65536, stream>>>(
      qw, ctx, attn, C_, (long)Q_ * C_, (long)S_ * C_, (long)S_,
      (long)C_, (long)C_, (long)B_ * S_, 0, ctxT, (long)S_);

  // 3) sequential coverage-softmax scan (in-place attention + accum + bf16 copy)
  scan_kernel<<<B_, 512, 0, stream>>>(mask, attn, accum_out, attnb);

  // 4) composition[q,b,c] = sum_s attnb[b,q,s] * ctxT[b,c,s]
  gemm_bf16<<<dim3(C_ / 128, 1, B_), 256, 32768, stream>>>(
      attnb, ctxT, comp, S_, (long)Q_ * S_, (long)C_ * S_, (long)C_,
      (long)S_, (long)S_, (long)B_ * C_);
}

// Round 16
// 378.655 us; speedup vs baseline: 1.0647x; 1.0639x over previous
//
#include <hip/hip_runtime.h>

#define B_ 32
#define Q_ 128
#define S_ 2048
#define C_ 1024
#define D_ 1024

typedef __attribute__((ext_vector_type(8))) short bf16x8;
typedef __attribute__((ext_vector_type(4))) float f32x4;

static __device__ __forceinline__ unsigned short f2bf(float f) {
  unsigned int u = __float_as_uint(f);
  u = (u + 0x7FFFu + ((u >> 16) & 1u)) >> 16;
  return (unsigned short)u;
}
static __device__ __forceinline__ float bf2f(unsigned short h) {
  return __uint_as_float(((unsigned int)h) << 16);
}

// async 16B global->LDS (DMA; dest = wave-uniform base + lane*16)
static __device__ __forceinline__ void gl_lds16(const float* g, float* l) {
  __builtin_amdgcn_global_load_lds(
      (const __attribute__((address_space(1))) unsigned int*)g,
      (__attribute__((address_space(3))) unsigned int*)l, 16, 0, 0);
}

// split 8 f32 (two f32x4) into hi/lo bf16x8 (rounded hi, rounded residual)
static __device__ __forceinline__ void split8(const f32x4 x0, const f32x4 x1,
                                              bf16x8& hi, bf16x8& lo) {
  float v[8] = {x0[0], x0[1], x0[2], x0[3], x1[0], x1[1], x1[2], x1[3]};
#pragma unroll
  for (int e = 0; e < 8; ++e) {
    const unsigned short h = f2bf(v[e]);
    hi[e] = (short)h;
    lo[e] = (short)f2bf(v[e] - bf2f(h));
  }
}

// ---------------------------------------------------------------------------
// f32-input split GEMM, BK=32, 128x128 tile, DOUBLE-BUFFERED global_load_lds
// pipeline with counted vmcnt (T3/T4): loads for tile t+1 stay in flight
// across the barriers of step t; vmcnt never drains to 0 in the main loop.
//   LDS: sA,sB = [2][128][32] f32 (16KB per buffer, 64KB total).
//   Swizzle: LDS[r][chunk p] = global chunk p ^ (r&7) (16B chunks; source
//   pre-swizzled so the DMA's linear lane map lands swizzled; reads XOR back).
//   Per step per wave: 8 DMA issues (4 A + 4 B).
//   Step: vmcnt(8) -> s_barrier -> compute(buf[t&1]) (+FUSE) -> s_barrier
//         -> STAGE(t+2 -> buf[t&1]).
// K-chunk order identical to the BK=64/kk=2 version -> bit-identical output.
// FUSE: write bf16(B-tile) transposed to fuseOut[bz][k][n] (free ctxT).
// ---------------------------------------------------------------------------
template <bool FUSE>
__global__ __launch_bounds__(256, 2)
void gemm_f32(const float* __restrict__ Aip, const float* __restrict__ Bip,
              float* __restrict__ outp, int K,
              long aBatch, long bBatch, long outBatch,
              long aRstride, long bRstride, long outRstride, int remapQB,
              unsigned short* __restrict__ fuseOut, long fuseRstride) {
  extern __shared__ char smem[];
  float* sA = (float*)smem;            // [2][4096] f32
  float* sB = sA + 8192;               // [2][4096] f32

  const int tid = threadIdx.x;
  const int lane = tid & 63;
  const int w = tid >> 6;              // wave 0..3
  const int wr = w >> 1;
  const int wc = w & 1;
  const int m0 = blockIdx.y * 128;
  const int n0 = blockIdx.x * 128;
  const int bz = blockIdx.z;
  const int frow = lane & 15;
  const int cc = lane >> 4;            // K-subchunk 0..3

  const float* Af = Aip + (long)bz * aBatch;
  const float* Bf = Bip + (long)bz * bBatch;

  f32x4 acc[4][4];
#pragma unroll
  for (int i = 0; i < 4; ++i)
#pragma unroll
    for (int j = 0; j < 4; ++j) acc[i][j] = (f32x4){0.f, 0.f, 0.f, 0.f};

  // stage one 128x32 K-tile pair (A+B) into buffer bufi: 8 issues/wave
  auto STAGE = [&](int ktt, int bufi) {
#pragma unroll
    for (int i = 0; i < 4; ++i) {
      const int rr = (w * 4 + i) * 8 + (lane >> 3);   // tile row 0..127
      const int cs = (lane & 7) ^ (rr & 7);           // pre-swizzled src chunk
      gl_lds16(Af + (long)(m0 + rr) * aRstride + ktt + cs * 4,
               sA + bufi * 4096 + (w * 4 + i) * 256);
    }
#pragma unroll
    for (int i = 0; i < 4; ++i) {
      const int rr = (w * 4 + i) * 8 + (lane >> 3);
      const int cs = (lane & 7) ^ (rr & 7);
      gl_lds16(Bf + (long)(n0 + rr) * bRstride + ktt + cs * 4,
               sB + bufi * 4096 + (w * 4 + i) * 256);
    }
  };

  const int nt = K >> 5;   // 32 steps at K=1024
  STAGE(0, 0);
  STAGE(32, 1);

  for (int t = 0; t < nt; ++t) {
    // wait for tile t (keep tile t+1's 8 loads in flight); full drain only at the end
    if (t + 1 < nt) { asm volatile("s_waitcnt vmcnt(8)" ::: "memory"); }
    else            { asm volatile("s_waitcnt vmcnt(0)" ::: "memory"); }
    __builtin_amdgcn_sched_barrier(0);
    asm volatile("s_barrier" ::: "memory");

    const float* sAb = sA + (t & 1) * 4096;
    const float* sBb = sB + (t & 1) * 4096;

    bf16x8 ah[4], al[4], bh[4], bl[4];
#pragma unroll
    for (int i = 0; i < 4; ++i) {
      const int row = wr * 64 + i * 16 + frow;
      const int c0 = ((cc * 2) ^ (row & 7)) << 2;
      const int c1 = ((cc * 2 + 1) ^ (row & 7)) << 2;
      split8(*(const f32x4*)(sAb + row * 32 + c0),
             *(const f32x4*)(sAb + row * 32 + c1), ah[i], al[i]);
    }
#pragma unroll
    for (int j = 0; j < 4; ++j) {
      const int row = wc * 64 + j * 16 + frow;
      const int c0 = ((cc * 2) ^ (row & 7)) << 2;
      const int c1 = ((cc * 2 + 1) ^ (row & 7)) << 2;
      split8(*(const f32x4*)(sBb + row * 32 + c0),
             *(const f32x4*)(sBb + row * 32 + c1), bh[j], bl[j]);
    }
#pragma unroll
    for (int i = 0; i < 4; ++i)
#pragma unroll
      for (int j = 0; j < 4; ++j) {
        acc[i][j] = __builtin_amdgcn_mfma_f32_16x16x32_bf16(ah[i], bh[j], acc[i][j], 0, 0, 0);
        acc[i][j] = __builtin_amdgcn_mfma_f32_16x16x32_bf16(ah[i], bl[j], acc[i][j], 0, 0, 0);
        acc[i][j] = __builtin_amdgcn_mfma_f32_16x16x32_bf16(al[i], bh[j], acc[i][j], 0, 0, 0);
      }

    // fused bf16 transposed write-out of the B tile (ctxT rows kt..kt+31)
    // thread: k = tid>>3 (0..31), n-range (tid&7)*16..+15; per 16-lane phase
    // the 8 rows x 2 k map to 16 distinct banks (conflict-free).
    if constexpr (FUSE) {
      const int k = tid >> 3;
      const int nf = (tid & 7) * 16;
      unsigned short vals[16];
#pragma unroll
      for (int i = 0; i < 16; ++i) {
        const int row = nf + i;
        vals[i] = f2bf(sBb[row * 32 + (((k >> 2) ^ (row & 7)) << 2) + (k & 3)]);
      }
      unsigned short* dst = fuseOut + ((long)bz * K + t * 32 + k) * fuseRstride + n0 + nf;
      *(bf16x8*)(dst + 0) = *(const bf16x8*)(vals + 0);
      *(bf16x8*)(dst + 8) = *(const bf16x8*)(vals + 8);
    }

    asm volatile("s_barrier" ::: "memory");
    if (t + 2 < nt) STAGE((t + 2) * 32, t & 1);
  }

  float* out = outp + (long)bz * outBatch;
#pragma unroll
  for (int i = 0; i < 4; ++i) {
#pragma unroll
    for (int rr = 0; rr < 4; ++rr) {
      const int grow = m0 + wr * 64 + i * 16 + ((lane >> 4) << 2) + rr;
      const long orow = remapQB ? ((long)(grow & 31) * 128 + (grow >> 5)) : (long)grow;
      float* orp = out + orow * outRstride;
#pragma unroll
      for (int j = 0; j < 4; ++j) {
        const int col = n0 + wc * 64 + j * 16 + (lane & 15);
        orp[col] = acc[i][j][rr];
      }
    }
  }
}

// ---------------------------------------------------------------------------
// bf16 copy GEMM (round-11 proven, verbatim): BK=64, reg staging, XOR-16B
// swizzle. Used for the composition GEMM only.
// ---------------------------------------------------------------------------
static __device__ __forceinline__ void stage_copy(unsigned short* dst,
                                                  const unsigned short* base,
                                                  long rstride, int kt, int tid) {
  const int r = tid >> 1;
  const int sc = (tid & 1) << 5;
  const int swz = (r & 7) << 4;
  const unsigned short* s = base + (long)r * rstride + kt + sc;
  char* row = (char*)dst + r * 128;
#pragma unroll
  for (int j = 0; j < 4; ++j)
    *(bf16x8*)(row + ((sc * 2 + j * 16) ^ swz)) = *(const bf16x8*)(s + j * 8);
}

__global__ __launch_bounds__(256, 2)
void gemm_bf16(const unsigned short* __restrict__ Aip, const unsigned short* __restrict__ Bip,
               float* __restrict__ outp, int K,
               long aBatch, long bBatch, long outBatch,
               long aRstride, long bRstride, long outRstride) {
  extern __shared__ char smem[];
  unsigned short* sA = (unsigned short*)smem;   // [128][64]
  unsigned short* sB = sA + 128 * 64;

  const int tid = threadIdx.x;
  const int lane = tid & 63;
  const int wid = tid >> 6;
  const int wr = wid >> 1;
  const int wc = wid & 1;
  const int m0 = blockIdx.y * 128;
  const int n0 = blockIdx.x * 128;
  const int bz = blockIdx.z;
  const int frow = lane & 15;

  f32x4 acc[4][4];
#pragma unroll
  for (int i = 0; i < 4; ++i)
#pragma unroll
    for (int j = 0; j < 4; ++j) acc[i][j] = (f32x4){0.f, 0.f, 0.f, 0.f};

  for (int kt = 0; kt < K; kt += 64) {
    stage_copy(sA, Aip + (long)bz * aBatch + (long)m0 * aRstride, aRstride, kt, tid);
    stage_copy(sB, Bip + (long)bz * bBatch + (long)n0 * bRstride, bRstride, kt, tid);
    __syncthreads();

#pragma unroll
    for (int kk = 0; kk < 2; ++kk) {
      const int kb = kk * 64 + ((lane >> 4) << 4);
      bf16x8 ah[4], bh[4];
#pragma unroll
      for (int i = 0; i < 4; ++i) {
        const int row = wr * 64 + i * 16 + frow;
        ah[i] = *(const bf16x8*)((const char*)sA + row * 128 + (kb ^ ((row & 7) << 4)));
      }
#pragma unroll
      for (int j = 0; j < 4; ++j) {
        const int row = wc * 64 + j * 16 + frow;
        bh[j] = *(const bf16x8*)((const char*)sB + row * 128 + (kb ^ ((row & 7) << 4)));
      }
#pragma unroll
      for (int i = 0; i < 4; ++i)
#pragma unroll
        for (int j = 0; j < 4; ++j)
          acc[i][j] = __builtin_amdgcn_mfma_f32_16x16x32_bf16(ah[i], bh[j], acc[i][j], 0, 0, 0);
    }
    __syncthreads();
  }

  float* out = outp + (long)bz * outBatch;
#pragma unroll
  for (int i = 0; i < 4; ++i) {
#pragma unroll
    for (int rr = 0; rr < 4; ++rr) {
      const int grow = m0 + wr * 64 + i * 16 + ((lane >> 4) << 2) + rr;
      float* orp = out + (long)grow * outRstride;
#pragma unroll
      for (int j = 0; j < 4; ++j) {
        const int col = n0 + wc * 64 + j * 16 + (lane & 15);
        orp[col] = acc[i][j][rr];
      }
    }
  }
}

// ---------------------------------------------------------------------------
// Scan (round-9/11 proven, verbatim): 512 threads/block, 4 cols/thread.
// asm prefetch depth 2 + counted vmcnt (3 VMEM/row -> ladder 1/3/5); one raw
// s_barrier per row; parity double-buffered LDS (m,s); exact wave max.
// ---------------------------------------------------------------------------
template <int VM>
static __device__ __forceinline__ void scan_row(
    float* __restrict__ attn, unsigned short* __restrict__ attnb,
    int b, int q, int lane, int wid, int s0,
    const bool* msk, float* acc, f32x4& buf, float2 (&red)[2][8]) {
  const float L2E = 1.4426950408889634f;

  if constexpr (VM == 1)      asm volatile("s_waitcnt vmcnt(1)" ::: "memory");
  else if constexpr (VM == 3) asm volatile("s_waitcnt vmcnt(3)" ::: "memory");
  else                        asm volatile("s_waitcnt vmcnt(5)" ::: "memory");
  __builtin_amdgcn_sched_barrier(0);

  float adj[4];
#pragma unroll
  for (int j = 0; j < 4; ++j)
    adj[j] = msk[j] ? -1e30f : (buf[j] - acc[j]);

  int pr = q + 2; if (pr > Q_ - 1) pr = Q_ - 1;
  const float* pp = attn + ((long)(pr * B_ + b)) * S_ + s0;
  asm volatile("global_load_dwordx4 %0, %1, off"
               : "=&v"(buf)
               : "v"(pp), "v"(adj[0]), "v"(adj[1]), "v"(adj[2]), "v"(adj[3])
               : "memory");

  float lm = fmaxf(fmaxf(adj[0], adj[1]), fmaxf(adj[2], adj[3]));
#pragma unroll
  for (int off = 32; off > 0; off >>= 1) lm = fmaxf(lm, __shfl_xor(lm, off));

  float e[4];
#pragma unroll
  for (int j = 0; j < 4; ++j) {
    const float x = exp2f((adj[j] - lm) * L2E);
    e[j] = msk[j] ? 0.f : x;
  }

  float ls = (e[0] + e[1]) + (e[2] + e[3]);
#pragma unroll
  for (int off = 32; off > 0; off >>= 1) ls += __shfl_xor(ls, off);

  const int p = q & 1;
  if (lane == 0) red[p][wid] = make_float2(lm, ls);
  asm volatile("s_waitcnt lgkmcnt(0)\n\ts_barrier" ::: "memory");

  const float2 v0 = red[p][0], v1 = red[p][1], v2 = red[p][2], v3 = red[p][3];
  const float2 v4 = red[p][4], v5 = red[p][5], v6 = red[p][6], v7 = red[p][7];
  const float M = fmaxf(fmaxf(fmaxf(v0.x, v1.x), fmaxf(v2.x, v3.x)),
                        fmaxf(fmaxf(v4.x, v5.x), fmaxf(v6.x, v7.x)));
  const float tot = v0.y * exp2f((v0.x - M) * L2E) + v1.y * exp2f((v1.x - M) * L2E) +
                    v2.y * exp2f((v2.x - M) * L2E) + v3.y * exp2f((v3.x - M) * L2E) +
                    v4.y * exp2f((v4.x - M) * L2E) + v5.y * exp2f((v5.x - M) * L2E) +
                    v6.y * exp2f((v6.x - M) * L2E) + v7.y * exp2f((v7.x - M) * L2E);
  const float scale = exp2f((lm - M) * L2E) / tot;

  f32x4 av;
#pragma unroll
  for (int j = 0; j < 4; ++j) {
    av[j] = e[j] * scale;
    acc[j] += av[j];
  }
  *(f32x4*)(attn + ((long)(q * B_ + b)) * S_ + s0) = av;
  uint2 pk;
  pk.x = (unsigned int)f2bf(av[0]) | ((unsigned int)f2bf(av[1]) << 16);
  pk.y = (unsigned int)f2bf(av[2]) | ((unsigned int)f2bf(av[3]) << 16);
  *(uint2*)(attnb + ((long)b * Q_ + q) * S_ + s0) = pk;
}

__global__ __launch_bounds__(512)
void scan_kernel(const int* __restrict__ mask, float* __restrict__ attn,
                 float* __restrict__ accum_out, unsigned short* __restrict__ attnb) {
  const int b = blockIdx.x;
  const int tid = threadIdx.x;
  const int lane = tid & 63;
  const int wid = tid >> 6;
  const int s0 = tid * 4;

  __shared__ float2 red[2][8];

  const int4 mk = *(const int4*)(mask + (long)b * S_ + s0);
  const bool msk[4] = {mk.x != 0, mk.y != 0, mk.z != 0, mk.w != 0};
  asm volatile("" :: "v"(mk.x), "v"(mk.y), "v"(mk.z), "v"(mk.w));

  float acc[4] = {0.f, 0.f, 0.f, 0.f};

  f32x4 bufE, bufO;
  const float* p0 = attn + (long)b * S_ + s0;
  asm volatile("global_load_dwordx4 %0, %1, off" : "=&v"(bufE) : "v"(p0) : "memory");
  const float* p1 = attn + ((long)(B_ + b)) * S_ + s0;
  asm volatile("global_load_dwordx4 %0, %1, off" : "=&v"(bufO) : "v"(p1) : "memory");

  scan_row<1>(attn, attnb, b, 0, lane, wid, s0, msk, acc, bufE, red);
  scan_row<3>(attn, attnb, b, 1, lane, wid, s0, msk, acc, bufO, red);
  for (int q = 2; q < Q_; q += 2) {
    scan_row<5>(attn, attnb, b, q,     lane, wid, s0, msk, acc, bufE, red);
    scan_row<5>(attn, attnb, b, q + 1, lane, wid, s0, msk, acc, bufO, red);
  }

  f32x4 a4;
#pragma unroll
  for (int j = 0; j < 4; ++j) a4[j] = acc[j];
  *(f32x4*)(accum_out + (long)b * S_ + s0) = a4;
}

extern "C" void kernel_launch(void* const* d_in, const int* in_sizes, int n_in,
                              void* d_out, int out_size, void* d_ws, size_t ws_size,
                              hipStream_t stream) {
  const float* ctx   = (const float*)d_in[0];  // [B,S,C] f32
  const float* query = (const float*)d_in[1];  // [Q,B,D] f32
  const int*   mask  = (const int*)d_in[2];    // [B,S] int32 (bool)
  const float* W     = (const float*)d_in[3];  // [C,D] f32

  float* out = (float*)d_out;
  float* attn = out;                                      // [Q,B,S]
  float* accum_out = out + (size_t)Q_ * B_ * S_;          // [B,1,S]
  float* comp = accum_out + (size_t)B_ * S_;              // [Q,B,C]

  char* ws = (char*)d_ws;
  float* qw = (float*)ws;                                                   // [B,Q,C] f32, 16 MiB
  unsigned short* ctxT  = (unsigned short*)(ws + (size_t)16 * 1024 * 1024); // [B,C,S] bf16, 128 MiB
  unsigned short* attnb = (unsigned short*)(ws + (size_t)16 * 1024 * 1024 +
                                            (size_t)B_ * C_ * S_ * 2);      // [B,Q,S] bf16, 16 MiB

  // 1) QW[b,q,c] = sum_d query[q,b,d] * W[c,d]  (3-pass split, pipelined DMA)
  gemm_f32<false><<<dim3(C_ / 128, (Q_ * B_) / 128, 1), 256, 65536, stream>>>(
      query, W, qw, D_, 0L, 0L, 0L, (long)D_, (long)D_, (long)C_, 1, nullptr, 0L);

  // 2) scores[q,b,s] = sum_c QW[b,q,c] * ctx[b,s,c]  + fused ctxT write-out
  gemm_f32<true><<<dim3(S_ / 128, 1, B_), 256, 65536, stream>>>(
      qw, ctx, attn, C_, (long)Q_ * C_, (long)S_ * C_, (long)S_,
      (long)C_, (long)C_, (long)B_ * S_, 0, ctxT, (long)S_);

  // 3) sequential coverage-softmax scan (in-place attention + accum + bf16 copy)
  scan_kernel<<<B_, 512, 0, stream>>>(mask, attn, accum_out, attnb);

  // 4) composition[q,b,c] = sum_s attnb[b,q,s] * ctxT[b,c,s]
  gemm_bf16<<<dim3(C_ / 128, 1, B_), 256, 32768, stream>>>(
      attnb, ctxT, comp, S_, (long)Q_ * S_, (long)C_ * S_, (long)C_,
      (long)S_, (long)S_, (long)B_ * C_);
}

// Round 17
// 374.692 us; speedup vs baseline: 1.0760x; 1.0106x over previous
//
#include <hip/hip_runtime.h>

#define B_ 32
#define Q_ 128
#define S_ 2048
#define C_ 1024
#define D_ 1024

typedef __attribute__((ext_vector_type(8))) short bf16x8;
typedef __attribute__((ext_vector_type(4))) float f32x4;

static __device__ __forceinline__ unsigned short f2bf(float f) {
  unsigned int u = __float_as_uint(f);
  u = (u + 0x7FFFu + ((u >> 16) & 1u)) >> 16;
  return (unsigned short)u;
}
static __device__ __forceinline__ float bf2f(unsigned short h) {
  return __uint_as_float(((unsigned int)h) << 16);
}

// async 16B global->LDS (DMA; dest = wave-uniform base + lane*16)
static __device__ __forceinline__ void gl_lds16(const float* g, float* l) {
  __builtin_amdgcn_global_load_lds(
      (const __attribute__((address_space(1))) unsigned int*)g,
      (__attribute__((address_space(3))) unsigned int*)l, 16, 0, 0);
}

// split 8 f32 (two f32x4) into hi/lo bf16x8 (rounded hi, rounded residual)
static __device__ __forceinline__ void split8(const f32x4 x0, const f32x4 x1,
                                              bf16x8& hi, bf16x8& lo) {
  float v[8] = {x0[0], x0[1], x0[2], x0[3], x1[0], x1[1], x1[2], x1[3]};
#pragma unroll
  for (int e = 0; e < 8; ++e) {
    const unsigned short h = f2bf(v[e]);
    hi[e] = (short)h;
    lo[e] = (short)f2bf(v[e] - bf2f(h));
  }
}

// ---------------------------------------------------------------------------
// f32-input split GEMM, BK=32, 128x128 tile, DOUBLE-BUFFERED global_load_lds
// pipeline with counted vmcnt (T3/T4): tile t+1's 8 loads stay in flight
// across step t's barriers; vmcnt never drains to 0 in the main loop.
//   LDS: sA,sB = [2][128][32] f32. Chunk swizzle: LDS[r][p] = global chunk
//   p^(r&7) (source pre-swizzled; reads XOR back; fragment reads 2-way free).
//   Step: vmcnt(8) -> s_barrier -> compute(buf) (+FUSE) -> s_barrier
//         -> STAGE(t+2 -> buf).
// FUSE readout (fixed this round): k = lane&31, nbase = w*32+(lane>>5)*16.
//   Per iteration the 32 low lanes hit all 32 banks exactly once (bijection
//   ((k>>2)^c)*4+(k&3)), high lanes repeat on row+16 -> 2/bank = free.
//   Global: lanes {k,k+32} give 64B-contiguous segments per k-row.
// ---------------------------------------------------------------------------
template <bool FUSE>
__global__ __launch_bounds__(256, 2)
void gemm_f32(const float* __restrict__ Aip, const float* __restrict__ Bip,
              float* __restrict__ outp, int K,
              long aBatch, long bBatch, long outBatch,
              long aRstride, long bRstride, long outRstride, int remapQB,
              unsigned short* __restrict__ fuseOut, long fuseRstride) {
  extern __shared__ char smem[];
  float* sA = (float*)smem;            // [2][4096] f32
  float* sB = sA + 8192;               // [2][4096] f32

  const int tid = threadIdx.x;
  const int lane = tid & 63;
  const int w = tid >> 6;              // wave 0..3
  const int wr = w >> 1;
  const int wc = w & 1;
  const int m0 = blockIdx.y * 128;
  const int n0 = blockIdx.x * 128;
  const int bz = blockIdx.z;
  const int frow = lane & 15;
  const int cc = lane >> 4;            // K-subchunk 0..3

  const float* Af = Aip + (long)bz * aBatch;
  const float* Bf = Bip + (long)bz * bBatch;

  f32x4 acc[4][4];
#pragma unroll
  for (int i = 0; i < 4; ++i)
#pragma unroll
    for (int j = 0; j < 4; ++j) acc[i][j] = (f32x4){0.f, 0.f, 0.f, 0.f};

  // stage one 128x32 K-tile pair (A+B) into buffer bufi: 8 issues/wave
  auto STAGE = [&](int ktt, int bufi) {
#pragma unroll
    for (int i = 0; i < 4; ++i) {
      const int rr = (w * 4 + i) * 8 + (lane >> 3);   // tile row 0..127
      const int cs = (lane & 7) ^ (rr & 7);           // pre-swizzled src chunk
      gl_lds16(Af + (long)(m0 + rr) * aRstride + ktt + cs * 4,
               sA + bufi * 4096 + (w * 4 + i) * 256);
    }
#pragma unroll
    for (int i = 0; i < 4; ++i) {
      const int rr = (w * 4 + i) * 8 + (lane >> 3);
      const int cs = (lane & 7) ^ (rr & 7);
      gl_lds16(Bf + (long)(n0 + rr) * bRstride + ktt + cs * 4,
               sB + bufi * 4096 + (w * 4 + i) * 256);
    }
  };

  const int nt = K >> 5;   // 32 steps at K=1024
  STAGE(0, 0);
  STAGE(32, 1);

  for (int t = 0; t < nt; ++t) {
    // wait for tile t (keep tile t+1's 8 loads in flight); full drain at end
    if (t + 1 < nt) { asm volatile("s_waitcnt vmcnt(8)" ::: "memory"); }
    else            { asm volatile("s_waitcnt vmcnt(0)" ::: "memory"); }
    __builtin_amdgcn_sched_barrier(0);
    asm volatile("s_barrier" ::: "memory");

    const float* sAb = sA + (t & 1) * 4096;
    const float* sBb = sB + (t & 1) * 4096;

    bf16x8 ah[4], al[4], bh[4], bl[4];
#pragma unroll
    for (int i = 0; i < 4; ++i) {
      const int row = wr * 64 + i * 16 + frow;
      const int c0 = ((cc * 2) ^ (row & 7)) << 2;
      const int c1 = ((cc * 2 + 1) ^ (row & 7)) << 2;
      split8(*(const f32x4*)(sAb + row * 32 + c0),
             *(const f32x4*)(sAb + row * 32 + c1), ah[i], al[i]);
    }
#pragma unroll
    for (int j = 0; j < 4; ++j) {
      const int row = wc * 64 + j * 16 + frow;
      const int c0 = ((cc * 2) ^ (row & 7)) << 2;
      const int c1 = ((cc * 2 + 1) ^ (row & 7)) << 2;
      split8(*(const f32x4*)(sBb + row * 32 + c0),
             *(const f32x4*)(sBb + row * 32 + c1), bh[j], bl[j]);
    }
#pragma unroll
    for (int i = 0; i < 4; ++i)
#pragma unroll
      for (int j = 0; j < 4; ++j) {
        acc[i][j] = __builtin_amdgcn_mfma_f32_16x16x32_bf16(ah[i], bh[j], acc[i][j], 0, 0, 0);
        acc[i][j] = __builtin_amdgcn_mfma_f32_16x16x32_bf16(ah[i], bl[j], acc[i][j], 0, 0, 0);
        acc[i][j] = __builtin_amdgcn_mfma_f32_16x16x32_bf16(al[i], bh[j], acc[i][j], 0, 0, 0);
      }

    // fused bf16 transposed write-out of the B tile (ctxT rows kt..kt+31)
    // k = lane&31 fixed per lane; rows nbase..nbase+15. Conflict-free (see
    // header); lanes {k, k+32} form 64B-contiguous global segments per k.
    if constexpr (FUSE) {
      const int k = lane & 31;
      const int nb = w * 32 + ((lane >> 5) << 4);
      unsigned short vals[16];
#pragma unroll
      for (int i = 0; i < 16; ++i) {
        const int row = nb + i;
        vals[i] = f2bf(sBb[row * 32 + (((k >> 2) ^ (row & 7)) << 2) + (k & 3)]);
      }
      unsigned short* dst = fuseOut + ((long)bz * K + t * 32 + k) * fuseRstride + n0 + nb;
      *(bf16x8*)(dst + 0) = *(const bf16x8*)(vals + 0);
      *(bf16x8*)(dst + 8) = *(const bf16x8*)(vals + 8);
    }

    asm volatile("s_barrier" ::: "memory");
    if (t + 2 < nt) STAGE((t + 2) * 32, t & 1);
  }

  float* out = outp + (long)bz * outBatch;
#pragma unroll
  for (int i = 0; i < 4; ++i) {
#pragma unroll
    for (int rr = 0; rr < 4; ++rr) {
      const int grow = m0 + wr * 64 + i * 16 + ((lane >> 4) << 2) + rr;
      const long orow = remapQB ? ((long)(grow & 31) * 128 + (grow >> 5)) : (long)grow;
      float* orp = out + orow * outRstride;
#pragma unroll
      for (int j = 0; j < 4; ++j) {
        const int col = n0 + wc * 64 + j * 16 + (lane & 15);
        orp[col] = acc[i][j][rr];
      }
    }
  }
}

// ---------------------------------------------------------------------------
// bf16 copy GEMM (round-11 proven, verbatim): BK=64, reg staging, XOR-16B
// swizzle. Used for the composition GEMM only.
// ---------------------------------------------------------------------------
static __device__ __forceinline__ void stage_copy(unsigned short* dst,
                                                  const unsigned short* base,
                                                  long rstride, int kt, int tid) {
  const int r = tid >> 1;
  const int sc = (tid & 1) << 5;
  const int swz = (r & 7) << 4;
  const unsigned short* s = base + (long)r * rstride + kt + sc;
  char* row = (char*)dst + r * 128;
#pragma unroll
  for (int j = 0; j < 4; ++j)
    *(bf16x8*)(row + ((sc * 2 + j * 16) ^ swz)) = *(const bf16x8*)(s + j * 8);
}

__global__ __launch_bounds__(256, 2)
void gemm_bf16(const unsigned short* __restrict__ Aip, const unsigned short* __restrict__ Bip,
               float* __restrict__ outp, int K,
               long aBatch, long bBatch, long outBatch,
               long aRstride, long bRstride, long outRstride) {
  extern __shared__ char smem[];
  unsigned short* sA = (unsigned short*)smem;   // [128][64]
  unsigned short* sB = sA + 128 * 64;

  const int tid = threadIdx.x;
  const int lane = tid & 63;
  const int wid = tid >> 6;
  const int wr = wid >> 1;
  const int wc = wid & 1;
  const int m0 = blockIdx.y * 128;
  const int n0 = blockIdx.x * 128;
  const int bz = blockIdx.z;
  const int frow = lane & 15;

  f32x4 acc[4][4];
#pragma unroll
  for (int i = 0; i < 4; ++i)
#pragma unroll
    for (int j = 0; j < 4; ++j) acc[i][j] = (f32x4){0.f, 0.f, 0.f, 0.f};

  for (int kt = 0; kt < K; kt += 64) {
    stage_copy(sA, Aip + (long)bz * aBatch + (long)m0 * aRstride, aRstride, kt, tid);
    stage_copy(sB, Bip + (long)bz * bBatch + (long)n0 * bRstride, bRstride, kt, tid);
    __syncthreads();

#pragma unroll
    for (int kk = 0; kk < 2; ++kk) {
      const int kb = kk * 64 + ((lane >> 4) << 4);
      bf16x8 ah[4], bh[4];
#pragma unroll
      for (int i = 0; i < 4; ++i) {
        const int row = wr * 64 + i * 16 + frow;
        ah[i] = *(const bf16x8*)((const char*)sA + row * 128 + (kb ^ ((row & 7) << 4)));
      }
#pragma unroll
      for (int j = 0; j < 4; ++j) {
        const int row = wc * 64 + j * 16 + frow;
        bh[j] = *(const bf16x8*)((const char*)sB + row * 128 + (kb ^ ((row & 7) << 4)));
      }
#pragma unroll
      for (int i = 0; i < 4; ++i)
#pragma unroll
        for (int j = 0; j < 4; ++j)
          acc[i][j] = __builtin_amdgcn_mfma_f32_16x16x32_bf16(ah[i], bh[j], acc[i][j], 0, 0, 0);
    }
    __syncthreads();
  }

  float* out = outp + (long)bz * outBatch;
#pragma unroll
  for (int i = 0; i < 4; ++i) {
#pragma unroll
    for (int rr = 0; rr < 4; ++rr) {
      const int grow = m0 + wr * 64 + i * 16 + ((lane >> 4) << 2) + rr;
      float* orp = out + (long)grow * outRstride;
#pragma unroll
      for (int j = 0; j < 4; ++j) {
        const int col = n0 + wc * 64 + j * 16 + (lane & 15);
        orp[col] = acc[i][j][rr];
      }
    }
  }
}

// ---------------------------------------------------------------------------
// Scan (round-9/11 proven, verbatim): 512 threads/block, 4 cols/thread.
// asm prefetch depth 2 + counted vmcnt (3 VMEM/row -> ladder 1/3/5); one raw
// s_barrier per row; parity double-buffered LDS (m,s); exact wave max.
// ---------------------------------------------------------------------------
template <int VM>
static __device__ __forceinline__ void scan_row(
    float* __restrict__ attn, unsigned short* __restrict__ attnb,
    int b, int q, int lane, int wid, int s0,
    const bool* msk, float* acc, f32x4& buf, float2 (&red)[2][8]) {
  const float L2E = 1.4426950408889634f;

  if constexpr (VM == 1)      asm volatile("s_waitcnt vmcnt(1)" ::: "memory");
  else if constexpr (VM == 3) asm volatile("s_waitcnt vmcnt(3)" ::: "memory");
  else                        asm volatile("s_waitcnt vmcnt(5)" ::: "memory");
  __builtin_amdgcn_sched_barrier(0);

  float adj[4];
#pragma unroll
  for (int j = 0; j < 4; ++j)
    adj[j] = msk[j] ? -1e30f : (buf[j] - acc[j]);

  int pr = q + 2; if (pr > Q_ - 1) pr = Q_ - 1;
  const float* pp = attn + ((long)(pr * B_ + b)) * S_ + s0;
  asm volatile("global_load_dwordx4 %0, %1, off"
               : "=&v"(buf)
               : "v"(pp), "v"(adj[0]), "v"(adj[1]), "v"(adj[2]), "v"(adj[3])
               : "memory");

  float lm = fmaxf(fmaxf(adj[0], adj[1]), fmaxf(adj[2], adj[3]));
#pragma unroll
  for (int off = 32; off > 0; off >>= 1) lm = fmaxf(lm, __shfl_xor(lm, off));

  float e[4];
#pragma unroll
  for (int j = 0; j < 4; ++j) {
    const float x = exp2f((adj[j] - lm) * L2E);
    e[j] = msk[j] ? 0.f : x;
  }

  float ls = (e[0] + e[1]) + (e[2] + e[3]);
#pragma unroll
  for (int off = 32; off > 0; off >>= 1) ls += __shfl_xor(ls, off);

  const int p = q & 1;
  if (lane == 0) red[p][wid] = make_float2(lm, ls);
  asm volatile("s_waitcnt lgkmcnt(0)\n\ts_barrier" ::: "memory");

  const float2 v0 = red[p][0], v1 = red[p][1], v2 = red[p][2], v3 = red[p][3];
  const float2 v4 = red[p][4], v5 = red[p][5], v6 = red[p][6], v7 = red[p][7];
  const float M = fmaxf(fmaxf(fmaxf(v0.x, v1.x), fmaxf(v2.x, v3.x)),
                        fmaxf(fmaxf(v4.x, v5.x), fmaxf(v6.x, v7.x)));
  const float tot = v0.y * exp2f((v0.x - M) * L2E) + v1.y * exp2f((v1.x - M) * L2E) +
                    v2.y * exp2f((v2.x - M) * L2E) + v3.y * exp2f((v3.x - M) * L2E) +
                    v4.y * exp2f((v4.x - M) * L2E) + v5.y * exp2f((v5.x - M) * L2E) +
                    v6.y * exp2f((v6.x - M) * L2E) + v7.y * exp2f((v7.x - M) * L2E);
  const float scale = exp2f((lm - M) * L2E) / tot;

  f32x4 av;
#pragma unroll
  for (int j = 0; j < 4; ++j) {
    av[j] = e[j] * scale;
    acc[j] += av[j];
  }
  *(f32x4*)(attn + ((long)(q * B_ + b)) * S_ + s0) = av;
  uint2 pk;
  pk.x = (unsigned int)f2bf(av[0]) | ((unsigned int)f2bf(av[1]) << 16);
  pk.y = (unsigned int)f2bf(av[2]) | ((unsigned int)f2bf(av[3]) << 16);
  *(uint2*)(attnb + ((long)b * Q_ + q) * S_ + s0) = pk;
}

__global__ __launch_bounds__(512)
void scan_kernel(const int* __restrict__ mask, float* __restrict__ attn,
                 float* __restrict__ accum_out, unsigned short* __restrict__ attnb) {
  const int b = blockIdx.x;
  const int tid = threadIdx.x;
  const int lane = tid & 63;
  const int wid = tid >> 6;
  const int s0 = tid * 4;

  __shared__ float2 red[2][8];

  const int4 mk = *(const int4*)(mask + (long)b * S_ + s0);
  const bool msk[4] = {mk.x != 0, mk.y != 0, mk.z != 0, mk.w != 0};
  asm volatile("" :: "v"(mk.x), "v"(mk.y), "v"(mk.z), "v"(mk.w));

  float acc[4] = {0.f, 0.f, 0.f, 0.f};

  f32x4 bufE, bufO;
  const float* p0 = attn + (long)b * S_ + s0;
  asm volatile("global_load_dwordx4 %0, %1, off" : "=&v"(bufE) : "v"(p0) : "memory");
  const float* p1 = attn + ((long)(B_ + b)) * S_ + s0;
  asm volatile("global_load_dwordx4 %0, %1, off" : "=&v"(bufO) : "v"(p1) : "memory");

  scan_row<1>(attn, attnb, b, 0, lane, wid, s0, msk, acc, bufE, red);
  scan_row<3>(attn, attnb, b, 1, lane, wid, s0, msk, acc, bufO, red);
  for (int q = 2; q < Q_; q += 2) {
    scan_row<5>(attn, attnb, b, q,     lane, wid, s0, msk, acc, bufE, red);
    scan_row<5>(attn, attnb, b, q + 1, lane, wid, s0, msk, acc, bufO, red);
  }

  f32x4 a4;
#pragma unroll
  for (int j = 0; j < 4; ++j) a4[j] = acc[j];
  *(f32x4*)(accum_out + (long)b * S_ + s0) = a4;
}

extern "C" void kernel_launch(void* const* d_in, const int* in_sizes, int n_in,
                              void* d_out, int out_size, void* d_ws, size_t ws_size,
                              hipStream_t stream) {
  const float* ctx   = (const float*)d_in[0];  // [B,S,C] f32
  const float* query = (const float*)d_in[1];  // [Q,B,D] f32
  const int*   mask  = (const int*)d_in[2];    // [B,S] int32 (bool)
  const float* W     = (const float*)d_in[3];  // [C,D] f32

  float* out = (float*)d_out;
  float* attn = out;                                      // [Q,B,S]
  float* accum_out = out + (size_t)Q_ * B_ * S_;          // [B,1,S]
  float* comp = accum_out + (size_t)B_ * S_;              // [Q,B,C]

  char* ws = (char*)d_ws;
  float* qw = (float*)ws;                                                   // [B,Q,C] f32, 16 MiB
  unsigned short* ctxT  = (unsigned short*)(ws + (size_t)16 * 1024 * 1024); // [B,C,S] bf16, 128 MiB
  unsigned short* attnb = (unsigned short*)(ws + (size_t)16 * 1024 * 1024 +
                                            (size_t)B_ * C_ * S_ * 2);      // [B,Q,S] bf16, 16 MiB

  // 1) QW[b,q,c] = sum_d query[q,b,d] * W[c,d]  (3-pass split, pipelined DMA)
  gemm_f32<false><<<dim3(C_ / 128, (Q_ * B_) / 128, 1), 256, 65536, stream>>>(
      query, W, qw, D_, 0L, 0L, 0L, (long)D_, (long)D_, (long)C_, 1, nullptr, 0L);

  // 2) scores[q,b,s] = sum_c QW[b,q,c] * ctx[b,s,c]  + fused ctxT write-out
  gemm_f32<true><<<dim3(S_ / 128, 1, B_), 256, 65536, stream>>>(
      qw, ctx, attn, C_, (long)Q_ * C_, (long)S_ * C_, (long)S_,
      (long)C_, (long)C_, (long)B_ * S_, 0, ctxT, (long)S_);

  // 3) sequential coverage-softmax scan (in-place attention + accum + bf16 copy)
  scan_kernel<<<B_, 512, 0, stream>>>(mask, attn, accum_out, attnb);

  // 4) composition[q,b,c] = sum_s attnb[b,q,s] * ctxT[b,c,s]
  gemm_bf16<<<dim3(C_ / 128, 1, B_), 256, 32768, stream>>>(
      attnb, ctxT, comp, S_, (long)Q_ * S_, (long)C_ * S_, (long)C_,
      (long)S_, (long)S_, (long)B_ * C_);
}

// Round 18
// 352.012 us; speedup vs baseline: 1.1453x; 1.0644x over previous
//
#include <hip/hip_runtime.h>

#define B_ 32
#define Q_ 128
#define S_ 2048
#define C_ 1024
#define D_ 1024

typedef __attribute__((ext_vector_type(8))) short bf16x8;
typedef __attribute__((ext_vector_type(4))) float f32x4;
typedef __attribute__((ext_vector_type(4))) unsigned int u32x4;

static __device__ __forceinline__ unsigned short f2bf(float f) {
  unsigned int u = __float_as_uint(f);
  u = (u + 0x7FFFu + ((u >> 16) & 1u)) >> 16;
  return (unsigned short)u;
}
static __device__ __forceinline__ float bf2f(unsigned short h) {
  return __uint_as_float(((unsigned int)h) << 16);
}

// async 16B global->LDS (DMA; dest = wave-uniform base + lane*16)
static __device__ __forceinline__ void gl_lds16(const float* g, float* l) {
  __builtin_amdgcn_global_load_lds(
      (const __attribute__((address_space(1))) unsigned int*)g,
      (__attribute__((address_space(3))) unsigned int*)l, 16, 0, 0);
}

// TRUNCATION split of 8 f32 into hi/lo bf16x8 via v_perm_b32 packing.
//   hi = top 16 bits of v (truncated bf16; exact: v_hi = v & 0xffff0000)
//   r  = v - v_hi  (exact subtraction, low mantissa bits)
//   lo = top 16 bits of r (truncated bf16 of residual)
// v = hi + lo + eps, |eps| <~ 2^-15 |v| — score error ~1e-3 abs, invisible
// vs the 0.108 threshold. 6 VALU per 2 elems (2 AND + 2 SUB + 2 PERM) =
// ~3x fewer than the rounded f2bf version (round-16 VALUBusy 41%).
static __device__ __forceinline__ void split8(const f32x4 x0, const f32x4 x1,
                                              bf16x8& hi, bf16x8& lo) {
  u32x4 h, l;
#pragma unroll
  for (int p = 0; p < 2; ++p) {
    const unsigned int a0 = __float_as_uint(x0[2 * p]);
    const unsigned int a1 = __float_as_uint(x0[2 * p + 1]);
    h[p] = __builtin_amdgcn_perm(a1, a0, 0x07060302u);
    const float r0 = x0[2 * p]     - __uint_as_float(a0 & 0xffff0000u);
    const float r1 = x0[2 * p + 1] - __uint_as_float(a1 & 0xffff0000u);
    l[p] = __builtin_amdgcn_perm(__float_as_uint(r1), __float_as_uint(r0), 0x07060302u);
  }
#pragma unroll
  for (int p = 0; p < 2; ++p) {
    const unsigned int a0 = __float_as_uint(x1[2 * p]);
    const unsigned int a1 = __float_as_uint(x1[2 * p + 1]);
    h[2 + p] = __builtin_amdgcn_perm(a1, a0, 0x07060302u);
    const float r0 = x1[2 * p]     - __uint_as_float(a0 & 0xffff0000u);
    const float r1 = x1[2 * p + 1] - __uint_as_float(a1 & 0xffff0000u);
    l[2 + p] = __builtin_amdgcn_perm(__float_as_uint(r1), __float_as_uint(r0), 0x07060302u);
  }
  hi = __builtin_bit_cast(bf16x8, h);
  lo = __builtin_bit_cast(bf16x8, l);
}

// ---------------------------------------------------------------------------
// f32-input split GEMM, BK=32, 128x128 tile, DOUBLE-BUFFERED global_load_lds
// pipeline with counted vmcnt (T3/T4): tile t+1's 8 loads stay in flight
// across step t's barriers; vmcnt never drains to 0 in the main loop.
//   LDS: sA,sB = [2][128][32] f32. Chunk swizzle: LDS[r][p] = global chunk
//   p^(r&7) (source pre-swizzled; reads XOR back; fragment reads 2-way free).
//   Step: vmcnt(8) -> s_barrier -> compute(buf) (+FUSE) -> s_barrier
//         -> STAGE(t+2 -> buf).
// FUSE readout (round-17 proven): k = lane&31, nbase = w*32+(lane>>5)*16;
//   32 low lanes hit all 32 banks once per iter, high lanes 2/bank = free.
// ---------------------------------------------------------------------------
template <bool FUSE>
__global__ __launch_bounds__(256, 2)
void gemm_f32(const float* __restrict__ Aip, const float* __restrict__ Bip,
              float* __restrict__ outp, int K,
              long aBatch, long bBatch, long outBatch,
              long aRstride, long bRstride, long outRstride, int remapQB,
              unsigned short* __restrict__ fuseOut, long fuseRstride) {
  extern __shared__ char smem[];
  float* sA = (float*)smem;            // [2][4096] f32
  float* sB = sA + 8192;               // [2][4096] f32

  const int tid = threadIdx.x;
  const int lane = tid & 63;
  const int w = tid >> 6;              // wave 0..3
  const int wr = w >> 1;
  const int wc = w & 1;
  const int m0 = blockIdx.y * 128;
  const int n0 = blockIdx.x * 128;
  const int bz = blockIdx.z;
  const int frow = lane & 15;
  const int cc = lane >> 4;            // K-subchunk 0..3

  const float* Af = Aip + (long)bz * aBatch;
  const float* Bf = Bip + (long)bz * bBatch;

  f32x4 acc[4][4];
#pragma unroll
  for (int i = 0; i < 4; ++i)
#pragma unroll
    for (int j = 0; j < 4; ++j) acc[i][j] = (f32x4){0.f, 0.f, 0.f, 0.f};

  // stage one 128x32 K-tile pair (A+B) into buffer bufi: 8 issues/wave
  auto STAGE = [&](int ktt, int bufi) {
#pragma unroll
    for (int i = 0; i < 4; ++i) {
      const int rr = (w * 4 + i) * 8 + (lane >> 3);   // tile row 0..127
      const int cs = (lane & 7) ^ (rr & 7);           // pre-swizzled src chunk
      gl_lds16(Af + (long)(m0 + rr) * aRstride + ktt + cs * 4,
               sA + bufi * 4096 + (w * 4 + i) * 256);
    }
#pragma unroll
    for (int i = 0; i < 4; ++i) {
      const int rr = (w * 4 + i) * 8 + (lane >> 3);
      const int cs = (lane & 7) ^ (rr & 7);
      gl_lds16(Bf + (long)(n0 + rr) * bRstride + ktt + cs * 4,
               sB + bufi * 4096 + (w * 4 + i) * 256);
    }
  };

  const int nt = K >> 5;   // 32 steps at K=1024
  STAGE(0, 0);
  STAGE(32, 1);

  for (int t = 0; t < nt; ++t) {
    // wait for tile t (keep tile t+1's 8 loads in flight); full drain at end
    if (t + 1 < nt) { asm volatile("s_waitcnt vmcnt(8)" ::: "memory"); }
    else            { asm volatile("s_waitcnt vmcnt(0)" ::: "memory"); }
    __builtin_amdgcn_sched_barrier(0);
    asm volatile("s_barrier" ::: "memory");

    const float* sAb = sA + (t & 1) * 4096;
    const float* sBb = sB + (t & 1) * 4096;

    bf16x8 ah[4], al[4], bh[4], bl[4];
#pragma unroll
    for (int i = 0; i < 4; ++i) {
      const int row = wr * 64 + i * 16 + frow;
      const int c0 = ((cc * 2) ^ (row & 7)) << 2;
      const int c1 = ((cc * 2 + 1) ^ (row & 7)) << 2;
      split8(*(const f32x4*)(sAb + row * 32 + c0),
             *(const f32x4*)(sAb + row * 32 + c1), ah[i], al[i]);
    }
#pragma unroll
    for (int j = 0; j < 4; ++j) {
      const int row = wc * 64 + j * 16 + frow;
      const int c0 = ((cc * 2) ^ (row & 7)) << 2;
      const int c1 = ((cc * 2 + 1) ^ (row & 7)) << 2;
      split8(*(const f32x4*)(sBb + row * 32 + c0),
             *(const f32x4*)(sBb + row * 32 + c1), bh[j], bl[j]);
    }
#pragma unroll
    for (int i = 0; i < 4; ++i)
#pragma unroll
      for (int j = 0; j < 4; ++j) {
        acc[i][j] = __builtin_amdgcn_mfma_f32_16x16x32_bf16(ah[i], bh[j], acc[i][j], 0, 0, 0);
        acc[i][j] = __builtin_amdgcn_mfma_f32_16x16x32_bf16(ah[i], bl[j], acc[i][j], 0, 0, 0);
        acc[i][j] = __builtin_amdgcn_mfma_f32_16x16x32_bf16(al[i], bh[j], acc[i][j], 0, 0, 0);
      }

    // fused bf16 transposed write-out of the B tile (ctxT rows kt..kt+31)
    if constexpr (FUSE) {
      const int k = lane & 31;
      const int nb = w * 32 + ((lane >> 5) << 4);
      unsigned short vals[16];
#pragma unroll
      for (int i = 0; i < 16; ++i) {
        const int row = nb + i;
        vals[i] = f2bf(sBb[row * 32 + (((k >> 2) ^ (row & 7)) << 2) + (k & 3)]);
      }
      unsigned short* dst = fuseOut + ((long)bz * K + t * 32 + k) * fuseRstride + n0 + nb;
      *(bf16x8*)(dst + 0) = *(const bf16x8*)(vals + 0);
      *(bf16x8*)(dst + 8) = *(const bf16x8*)(vals + 8);
    }

    asm volatile("s_barrier" ::: "memory");
    if (t + 2 < nt) STAGE((t + 2) * 32, t & 1);
  }

  float* out = outp + (long)bz * outBatch;
#pragma unroll
  for (int i = 0; i < 4; ++i) {
#pragma unroll
    for (int rr = 0; rr < 4; ++rr) {
      const int grow = m0 + wr * 64 + i * 16 + ((lane >> 4) << 2) + rr;
      const long orow = remapQB ? ((long)(grow & 31) * 128 + (grow >> 5)) : (long)grow;
      float* orp = out + orow * outRstride;
#pragma unroll
      for (int j = 0; j < 4; ++j) {
        const int col = n0 + wc * 64 + j * 16 + (lane & 15);
        orp[col] = acc[i][j][rr];
      }
    }
  }
}

// ---------------------------------------------------------------------------
// bf16 copy GEMM (round-11 proven, verbatim): BK=64, reg staging, XOR-16B
// swizzle. Used for the composition GEMM only.
// ---------------------------------------------------------------------------
static __device__ __forceinline__ void stage_copy(unsigned short* dst,
                                                  const unsigned short* base,
                                                  long rstride, int kt, int tid) {
  const int r = tid >> 1;
  const int sc = (tid & 1) << 5;
  const int swz = (r & 7) << 4;
  const unsigned short* s = base + (long)r * rstride + kt + sc;
  char* row = (char*)dst + r * 128;
#pragma unroll
  for (int j = 0; j < 4; ++j)
    *(bf16x8*)(row + ((sc * 2 + j * 16) ^ swz)) = *(const bf16x8*)(s + j * 8);
}

__global__ __launch_bounds__(256, 2)
void gemm_bf16(const unsigned short* __restrict__ Aip, const unsigned short* __restrict__ Bip,
               float* __restrict__ outp, int K,
               long aBatch, long bBatch, long outBatch,
               long aRstride, long bRstride, long outRstride) {
  extern __shared__ char smem[];
  unsigned short* sA = (unsigned short*)smem;   // [128][64]
  unsigned short* sB = sA + 128 * 64;

  const int tid = threadIdx.x;
  const int lane = tid & 63;
  const int wid = tid >> 6;
  const int wr = wid >> 1;
  const int wc = wid & 1;
  const int m0 = blockIdx.y * 128;
  const int n0 = blockIdx.x * 128;
  const int bz = blockIdx.z;
  const int frow = lane & 15;

  f32x4 acc[4][4];
#pragma unroll
  for (int i = 0; i < 4; ++i)
#pragma unroll
    for (int j = 0; j < 4; ++j) acc[i][j] = (f32x4){0.f, 0.f, 0.f, 0.f};

  for (int kt = 0; kt < K; kt += 64) {
    stage_copy(sA, Aip + (long)bz * aBatch + (long)m0 * aRstride, aRstride, kt, tid);
    stage_copy(sB, Bip + (long)bz * bBatch + (long)n0 * bRstride, bRstride, kt, tid);
    __syncthreads();

#pragma unroll
    for (int kk = 0; kk < 2; ++kk) {
      const int kb = kk * 64 + ((lane >> 4) << 4);
      bf16x8 ah[4], bh[4];
#pragma unroll
      for (int i = 0; i < 4; ++i) {
        const int row = wr * 64 + i * 16 + frow;
        ah[i] = *(const bf16x8*)((const char*)sA + row * 128 + (kb ^ ((row & 7) << 4)));
      }
#pragma unroll
      for (int j = 0; j < 4; ++j) {
        const int row = wc * 64 + j * 16 + frow;
        bh[j] = *(const bf16x8*)((const char*)sB + row * 128 + (kb ^ ((row & 7) << 4)));
      }
#pragma unroll
      for (int i = 0; i < 4; ++i)
#pragma unroll
        for (int j = 0; j < 4; ++j)
          acc[i][j] = __builtin_amdgcn_mfma_f32_16x16x32_bf16(ah[i], bh[j], acc[i][j], 0, 0, 0);
    }
    __syncthreads();
  }

  float* out = outp + (long)bz * outBatch;
#pragma unroll
  for (int i = 0; i < 4; ++i) {
#pragma unroll
    for (int rr = 0; rr < 4; ++rr) {
      const int grow = m0 + wr * 64 + i * 16 + ((lane >> 4) << 2) + rr;
      float* orp = out + (long)grow * outRstride;
#pragma unroll
      for (int j = 0; j < 4; ++j) {
        const int col = n0 + wc * 64 + j * 16 + (lane & 15);
        orp[col] = acc[i][j][rr];
      }
    }
  }
}

// ---------------------------------------------------------------------------
// Scan (round-9/11 proven, verbatim): 512 threads/block, 4 cols/thread.
// asm prefetch depth 2 + counted vmcnt (3 VMEM/row -> ladder 1/3/5); one raw
// s_barrier per row; parity double-buffered LDS (m,s); exact wave max.
// ---------------------------------------------------------------------------
template <int VM>
static __device__ __forceinline__ void scan_row(
    float* __restrict__ attn, unsigned short* __restrict__ attnb,
    int b, int q, int lane, int wid, int s0,
    const bool* msk, float* acc, f32x4& buf, float2 (&red)[2][8]) {
  const float L2E = 1.4426950408889634f;

  if constexpr (VM == 1)      asm volatile("s_waitcnt vmcnt(1)" ::: "memory");
  else if constexpr (VM == 3) asm volatile("s_waitcnt vmcnt(3)" ::: "memory");
  else                        asm volatile("s_waitcnt vmcnt(5)" ::: "memory");
  __builtin_amdgcn_sched_barrier(0);

  float adj[4];
#pragma unroll
  for (int j = 0; j < 4; ++j)
    adj[j] = msk[j] ? -1e30f : (buf[j] - acc[j]);

  int pr = q + 2; if (pr > Q_ - 1) pr = Q_ - 1;
  const float* pp = attn + ((long)(pr * B_ + b)) * S_ + s0;
  asm volatile("global_load_dwordx4 %0, %1, off"
               : "=&v"(buf)
               : "v"(pp), "v"(adj[0]), "v"(adj[1]), "v"(adj[2]), "v"(adj[3])
               : "memory");

  float lm = fmaxf(fmaxf(adj[0], adj[1]), fmaxf(adj[2], adj[3]));
#pragma unroll
  for (int off = 32; off > 0; off >>= 1) lm = fmaxf(lm, __shfl_xor(lm, off));

  float e[4];
#pragma unroll
  for (int j = 0; j < 4; ++j) {
    const float x = exp2f((adj[j] - lm) * L2E);
    e[j] = msk[j] ? 0.f : x;
  }

  float ls = (e[0] + e[1]) + (e[2] + e[3]);
#pragma unroll
  for (int off = 32; off > 0; off >>= 1) ls += __shfl_xor(ls, off);

  const int p = q & 1;
  if (lane == 0) red[p][wid] = make_float2(lm, ls);
  asm volatile("s_waitcnt lgkmcnt(0)\n\ts_barrier" ::: "memory");

  const float2 v0 = red[p][0], v1 = red[p][1], v2 = red[p][2], v3 = red[p][3];
  const float2 v4 = red[p][4], v5 = red[p][5], v6 = red[p][6], v7 = red[p][7];
  const float M = fmaxf(fmaxf(fmaxf(v0.x, v1.x), fmaxf(v2.x, v3.x)),
                        fmaxf(fmaxf(v4.x, v5.x), fmaxf(v6.x, v7.x)));
  const float tot = v0.y * exp2f((v0.x - M) * L2E) + v1.y * exp2f((v1.x - M) * L2E) +
                    v2.y * exp2f((v2.x - M) * L2E) + v3.y * exp2f((v3.x - M) * L2E) +
                    v4.y * exp2f((v4.x - M) * L2E) + v5.y * exp2f((v5.x - M) * L2E) +
                    v6.y * exp2f((v6.x - M) * L2E) + v7.y * exp2f((v7.x - M) * L2E);
  const float scale = exp2f((lm - M) * L2E) / tot;

  f32x4 av;
#pragma unroll
  for (int j = 0; j < 4; ++j) {
    av[j] = e[j] * scale;
    acc[j] += av[j];
  }
  *(f32x4*)(attn + ((long)(q * B_ + b)) * S_ + s0) = av;
  uint2 pk;
  pk.x = (unsigned int)f2bf(av[0]) | ((unsigned int)f2bf(av[1]) << 16);
  pk.y = (unsigned int)f2bf(av[2]) | ((unsigned int)f2bf(av[3]) << 16);
  *(uint2*)(attnb + ((long)b * Q_ + q) * S_ + s0) = pk;
}

__global__ __launch_bounds__(512)
void scan_kernel(const int* __restrict__ mask, float* __restrict__ attn,
                 float* __restrict__ accum_out, unsigned short* __restrict__ attnb) {
  const int b = blockIdx.x;
  const int tid = threadIdx.x;
  const int lane = tid & 63;
  const int wid = tid >> 6;
  const int s0 = tid * 4;

  __shared__ float2 red[2][8];

  const int4 mk = *(const int4*)(mask + (long)b * S_ + s0);
  const bool msk[4] = {mk.x != 0, mk.y != 0, mk.z != 0, mk.w != 0};
  asm volatile("" :: "v"(mk.x), "v"(mk.y), "v"(mk.z), "v"(mk.w));

  float acc[4] = {0.f, 0.f, 0.f, 0.f};

  f32x4 bufE, bufO;
  const float* p0 = attn + (long)b * S_ + s0;
  asm volatile("global_load_dwordx4 %0, %1, off" : "=&v"(bufE) : "v"(p0) : "memory");
  const float* p1 = attn + ((long)(B_ + b)) * S_ + s0;
  asm volatile("global_load_dwordx4 %0, %1, off" : "=&v"(bufO) : "v"(p1) : "memory");

  scan_row<1>(attn, attnb, b, 0, lane, wid, s0, msk, acc, bufE, red);
  scan_row<3>(attn, attnb, b, 1, lane, wid, s0, msk, acc, bufO, red);
  for (int q = 2; q < Q_; q += 2) {
    scan_row<5>(attn, attnb, b, q,     lane, wid, s0, msk, acc, bufE, red);
    scan_row<5>(attn, attnb, b, q + 1, lane, wid, s0, msk, acc, bufO, red);
  }

  f32x4 a4;
#pragma unroll
  for (int j = 0; j < 4; ++j) a4[j] = acc[j];
  *(f32x4*)(accum_out + (long)b * S_ + s0) = a4;
}

extern "C" void kernel_launch(void* const* d_in, const int* in_sizes, int n_in,
                              void* d_out, int out_size, void* d_ws, size_t ws_size,
                              hipStream_t stream) {
  const float* ctx   = (const float*)d_in[0];  // [B,S,C] f32
  const float* query = (const float*)d_in[1];  // [Q,B,D] f32
  const int*   mask  = (const int*)d_in[2];    // [B,S] int32 (bool)
  const float* W     = (const float*)d_in[3];  // [C,D] f32

  float* out = (float*)d_out;
  float* attn = out;                                      // [Q,B,S]
  float* accum_out = out + (size_t)Q_ * B_ * S_;          // [B,1,S]
  float* comp = accum_out + (size_t)B_ * S_;              // [Q,B,C]

  char* ws = (char*)d_ws;
  float* qw = (float*)ws;                                                   // [B,Q,C] f32, 16 MiB
  unsigned short* ctxT  = (unsigned short*)(ws + (size_t)16 * 1024 * 1024); // [B,C,S] bf16, 128 MiB
  unsigned short* attnb = (unsigned short*)(ws + (size_t)16 * 1024 * 1024 +
                                            (size_t)B_ * C_ * S_ * 2);      // [B,Q,S] bf16, 16 MiB

  // 1) QW[b,q,c] = sum_d query[q,b,d] * W[c,d]  (3-pass split, pipelined DMA)
  gemm_f32<false><<<dim3(C_ / 128, (Q_ * B_) / 128, 1), 256, 65536, stream>>>(
      query, W, qw, D_, 0L, 0L, 0L, (long)D_, (long)D_, (long)C_, 1, nullptr, 0L);

  // 2) scores[q,b,s] = sum_c QW[b,q,c] * ctx[b,s,c]  + fused ctxT write-out
  gemm_f32<true><<<dim3(S_ / 128, 1, B_), 256, 65536, stream>>>(
      qw, ctx, attn, C_, (long)Q_ * C_, (long)S_ * C_, (long)S_,
      (long)C_, (long)C_, (long)B_ * S_, 0, ctxT, (long)S_);

  // 3) sequential coverage-softmax scan (in-place attention + accum + bf16 copy)
  scan_kernel<<<B_, 512, 0, stream>>>(mask, attn, accum_out, attnb);

  // 4) composition[q,b,c] = sum_s attnb[b,q,s] * ctxT[b,c,s]
  gemm_bf16<<<dim3(C_ / 128, 1, B_), 256, 32768, stream>>>(
      attnb, ctxT, comp, S_, (long)Q_ * S_, (long)C_ * S_, (long)C_,
      (long)S_, (long)S_, (long)B_ * C_);
}

// Round 19
// 338.076 us; speedup vs baseline: 1.1925x; 1.0412x over previous
//
#include <hip/hip_runtime.h>

#define B_ 32
#define Q_ 128
#define S_ 2048
#define C_ 1024
#define D_ 1024

typedef __attribute__((ext_vector_type(8))) short bf16x8;
typedef __attribute__((ext_vector_type(4))) float f32x4;
typedef __attribute__((ext_vector_type(4))) unsigned int u32x4;

static __device__ __forceinline__ unsigned short f2bf(float f) {
  unsigned int u = __float_as_uint(f);
  u = (u + 0x7FFFu + ((u >> 16) & 1u)) >> 16;
  return (unsigned short)u;
}
static __device__ __forceinline__ float bf2f(unsigned short h) {
  return __uint_as_float(((unsigned int)h) << 16);
}

// async 16B global->LDS (DMA; dest = wave-uniform base + lane*16)
static __device__ __forceinline__ void gl_lds16(const void* g, void* l) {
  __builtin_amdgcn_global_load_lds(
      (const __attribute__((address_space(1))) unsigned int*)g,
      (__attribute__((address_space(3))) unsigned int*)l, 16, 0, 0);
}

// TRUNCATION split of 8 f32 into hi/lo bf16x8 via v_perm_b32 packing
// (round-18 proven: hi = trunc-bf16(v), lo = trunc-bf16(v - hi); ~3x fewer
// VALU than rounded f2bf; score error ~1e-3 abs vs 0.108 threshold).
static __device__ __forceinline__ void split8(const f32x4 x0, const f32x4 x1,
                                              bf16x8& hi, bf16x8& lo) {
  u32x4 h, l;
#pragma unroll
  for (int p = 0; p < 2; ++p) {
    const unsigned int a0 = __float_as_uint(x0[2 * p]);
    const unsigned int a1 = __float_as_uint(x0[2 * p + 1]);
    h[p] = __builtin_amdgcn_perm(a1, a0, 0x07060302u);
    const float r0 = x0[2 * p]     - __uint_as_float(a0 & 0xffff0000u);
    const float r1 = x0[2 * p + 1] - __uint_as_float(a1 & 0xffff0000u);
    l[p] = __builtin_amdgcn_perm(__float_as_uint(r1), __float_as_uint(r0), 0x07060302u);
  }
#pragma unroll
  for (int p = 0; p < 2; ++p) {
    const unsigned int a0 = __float_as_uint(x1[2 * p]);
    const unsigned int a1 = __float_as_uint(x1[2 * p + 1]);
    h[2 + p] = __builtin_amdgcn_perm(a1, a0, 0x07060302u);
    const float r0 = x1[2 * p]     - __uint_as_float(a0 & 0xffff0000u);
    const float r1 = x1[2 * p + 1] - __uint_as_float(a1 & 0xffff0000u);
    l[2 + p] = __builtin_amdgcn_perm(__float_as_uint(r1), __float_as_uint(r0), 0x07060302u);
  }
  hi = __builtin_bit_cast(bf16x8, h);
  lo = __builtin_bit_cast(bf16x8, l);
}

// ---------------------------------------------------------------------------
// f32-input split GEMM (rounds 16-18 proven, verbatim): BK=32, 128x128 tile,
// double-buffered global_load_lds pipeline, counted vmcnt(8), raw barriers.
// FUSE: conflict-free bf16 transposed B-tile write-out (ctxT).
// ---------------------------------------------------------------------------
template <bool FUSE>
__global__ __launch_bounds__(256, 2)
void gemm_f32(const float* __restrict__ Aip, const float* __restrict__ Bip,
              float* __restrict__ outp, int K,
              long aBatch, long bBatch, long outBatch,
              long aRstride, long bRstride, long outRstride, int remapQB,
              unsigned short* __restrict__ fuseOut, long fuseRstride) {
  extern __shared__ char smem[];
  float* sA = (float*)smem;            // [2][4096] f32
  float* sB = sA + 8192;               // [2][4096] f32

  const int tid = threadIdx.x;
  const int lane = tid & 63;
  const int w = tid >> 6;              // wave 0..3
  const int wr = w >> 1;
  const int wc = w & 1;
  const int m0 = blockIdx.y * 128;
  const int n0 = blockIdx.x * 128;
  const int bz = blockIdx.z;
  const int frow = lane & 15;
  const int cc = lane >> 4;            // K-subchunk 0..3

  const float* Af = Aip + (long)bz * aBatch;
  const float* Bf = Bip + (long)bz * bBatch;

  f32x4 acc[4][4];
#pragma unroll
  for (int i = 0; i < 4; ++i)
#pragma unroll
    for (int j = 0; j < 4; ++j) acc[i][j] = (f32x4){0.f, 0.f, 0.f, 0.f};

  auto STAGE = [&](int ktt, int bufi) {
#pragma unroll
    for (int i = 0; i < 4; ++i) {
      const int rr = (w * 4 + i) * 8 + (lane >> 3);   // tile row 0..127
      const int cs = (lane & 7) ^ (rr & 7);           // pre-swizzled src chunk
      gl_lds16(Af + (long)(m0 + rr) * aRstride + ktt + cs * 4,
               sA + bufi * 4096 + (w * 4 + i) * 256);
    }
#pragma unroll
    for (int i = 0; i < 4; ++i) {
      const int rr = (w * 4 + i) * 8 + (lane >> 3);
      const int cs = (lane & 7) ^ (rr & 7);
      gl_lds16(Bf + (long)(n0 + rr) * bRstride + ktt + cs * 4,
               sB + bufi * 4096 + (w * 4 + i) * 256);
    }
  };

  const int nt = K >> 5;   // 32 steps at K=1024
  STAGE(0, 0);
  STAGE(32, 1);

  for (int t = 0; t < nt; ++t) {
    if (t + 1 < nt) { asm volatile("s_waitcnt vmcnt(8)" ::: "memory"); }
    else            { asm volatile("s_waitcnt vmcnt(0)" ::: "memory"); }
    __builtin_amdgcn_sched_barrier(0);
    asm volatile("s_barrier" ::: "memory");

    const float* sAb = sA + (t & 1) * 4096;
    const float* sBb = sB + (t & 1) * 4096;

    bf16x8 ah[4], al[4], bh[4], bl[4];
#pragma unroll
    for (int i = 0; i < 4; ++i) {
      const int row = wr * 64 + i * 16 + frow;
      const int c0 = ((cc * 2) ^ (row & 7)) << 2;
      const int c1 = ((cc * 2 + 1) ^ (row & 7)) << 2;
      split8(*(const f32x4*)(sAb + row * 32 + c0),
             *(const f32x4*)(sAb + row * 32 + c1), ah[i], al[i]);
    }
#pragma unroll
    for (int j = 0; j < 4; ++j) {
      const int row = wc * 64 + j * 16 + frow;
      const int c0 = ((cc * 2) ^ (row & 7)) << 2;
      const int c1 = ((cc * 2 + 1) ^ (row & 7)) << 2;
      split8(*(const f32x4*)(sBb + row * 32 + c0),
             *(const f32x4*)(sBb + row * 32 + c1), bh[j], bl[j]);
    }
#pragma unroll
    for (int i = 0; i < 4; ++i)
#pragma unroll
      for (int j = 0; j < 4; ++j) {
        acc[i][j] = __builtin_amdgcn_mfma_f32_16x16x32_bf16(ah[i], bh[j], acc[i][j], 0, 0, 0);
        acc[i][j] = __builtin_amdgcn_mfma_f32_16x16x32_bf16(ah[i], bl[j], acc[i][j], 0, 0, 0);
        acc[i][j] = __builtin_amdgcn_mfma_f32_16x16x32_bf16(al[i], bh[j], acc[i][j], 0, 0, 0);
      }

    if constexpr (FUSE) {
      const int k = lane & 31;
      const int nb = w * 32 + ((lane >> 5) << 4);
      unsigned short vals[16];
#pragma unroll
      for (int i = 0; i < 16; ++i) {
        const int row = nb + i;
        vals[i] = f2bf(sBb[row * 32 + (((k >> 2) ^ (row & 7)) << 2) + (k & 3)]);
      }
      unsigned short* dst = fuseOut + ((long)bz * K + t * 32 + k) * fuseRstride + n0 + nb;
      *(bf16x8*)(dst + 0) = *(const bf16x8*)(vals + 0);
      *(bf16x8*)(dst + 8) = *(const bf16x8*)(vals + 8);
    }

    asm volatile("s_barrier" ::: "memory");
    if (t + 2 < nt) STAGE((t + 2) * 32, t & 1);
  }

  float* out = outp + (long)bz * outBatch;
#pragma unroll
  for (int i = 0; i < 4; ++i) {
#pragma unroll
    for (int rr = 0; rr < 4; ++rr) {
      const int grow = m0 + wr * 64 + i * 16 + ((lane >> 4) << 2) + rr;
      const long orow = remapQB ? ((long)(grow & 31) * 128 + (grow >> 5)) : (long)grow;
      float* orp = out + orow * outRstride;
#pragma unroll
      for (int j = 0; j < 4; ++j) {
        const int col = n0 + wc * 64 + j * 16 + (lane & 15);
        orp[col] = acc[i][j][rr];
      }
    }
  }
}

// ---------------------------------------------------------------------------
// bf16 copy GEMM, NOW PIPELINED (this round's change): BK=64, 128x128 tile,
// DMA staging via global_load_lds with pre-swizzled source, double-buffered,
// counted vmcnt(8) (T3/T4), raw s_barriers. Tile layout and fragment reads
// are byte-identical to the round-11 reg-staged version (byte chunk kk*4+cc,
// XOR r&7, 2-way banks) -> bit-identical output.
//   LDS: sA,sB = [2][128][64] bf16 (16KB/buffer, 64KB total).
//   Per STAGE per wave: 4 A + 4 B issues (1KB each; 8 rows per issue).
// ---------------------------------------------------------------------------
__global__ __launch_bounds__(256, 2)
void gemm_bf16(const unsigned short* __restrict__ Aip, const unsigned short* __restrict__ Bip,
               float* __restrict__ outp, int K,
               long aBatch, long bBatch, long outBatch,
               long aRstride, long bRstride, long outRstride) {
  extern __shared__ char smem[];
  unsigned short* sA = (unsigned short*)smem;   // [2][8192] bf16
  unsigned short* sB = sA + 16384;              // [2][8192] bf16

  const int tid = threadIdx.x;
  const int lane = tid & 63;
  const int w = tid >> 6;
  const int wr = w >> 1;
  const int wc = w & 1;
  const int m0 = blockIdx.y * 128;
  const int n0 = blockIdx.x * 128;
  const int bz = blockIdx.z;
  const int frow = lane & 15;
  const int cc = lane >> 4;   // 0..3

  const unsigned short* Ab = Aip + (long)bz * aBatch;
  const unsigned short* Bb = Bip + (long)bz * bBatch;

  f32x4 acc[4][4];
#pragma unroll
  for (int i = 0; i < 4; ++i)
#pragma unroll
    for (int j = 0; j < 4; ++j) acc[i][j] = (f32x4){0.f, 0.f, 0.f, 0.f};

  // stage one 128x64 bf16 tile pair into buffer bufi: 8 issues/wave.
  // Issue i covers rows (w*4+i)*8 .. +7; lane l -> row +(l>>3), 16B chunk
  // (l&7), source chunk pre-swizzled by ^(row&7) so LDS lands swizzled.
  auto STAGE = [&](int ktt, int bufi) {
#pragma unroll
    for (int i = 0; i < 4; ++i) {
      const int rr = (w * 4 + i) * 8 + (lane >> 3);
      const int cs = (lane & 7) ^ (rr & 7);
      gl_lds16(Ab + (long)(m0 + rr) * aRstride + ktt + cs * 8,
               sA + bufi * 8192 + (w * 4 + i) * 512);
    }
#pragma unroll
    for (int i = 0; i < 4; ++i) {
      const int rr = (w * 4 + i) * 8 + (lane >> 3);
      const int cs = (lane & 7) ^ (rr & 7);
      gl_lds16(Bb + (long)(n0 + rr) * bRstride + ktt + cs * 8,
               sB + bufi * 8192 + (w * 4 + i) * 512);
    }
  };

  const int nt = K >> 6;   // 32 steps at K=2048
  STAGE(0, 0);
  STAGE(64, 1);

  for (int t = 0; t < nt; ++t) {
    if (t + 1 < nt) { asm volatile("s_waitcnt vmcnt(8)" ::: "memory"); }
    else            { asm volatile("s_waitcnt vmcnt(0)" ::: "memory"); }
    __builtin_amdgcn_sched_barrier(0);
    asm volatile("s_barrier" ::: "memory");

    const unsigned short* sAb = sA + (t & 1) * 8192;
    const unsigned short* sBb = sB + (t & 1) * 8192;

#pragma unroll
    for (int kk = 0; kk < 2; ++kk) {
      bf16x8 ah[4], bh[4];
#pragma unroll
      for (int i = 0; i < 4; ++i) {
        const int row = wr * 64 + i * 16 + frow;
        const int ch = kk * 4 + cc;
        ah[i] = *(const bf16x8*)((const char*)sAb + row * 128 + ((ch ^ (row & 7)) << 4));
      }
#pragma unroll
      for (int j = 0; j < 4; ++j) {
        const int row = wc * 64 + j * 16 + frow;
        const int ch = kk * 4 + cc;
        bh[j] = *(const bf16x8*)((const char*)sBb + row * 128 + ((ch ^ (row & 7)) << 4));
      }
#pragma unroll
      for (int i = 0; i < 4; ++i)
#pragma unroll
        for (int j = 0; j < 4; ++j)
          acc[i][j] = __builtin_amdgcn_mfma_f32_16x16x32_bf16(ah[i], bh[j], acc[i][j], 0, 0, 0);
    }

    asm volatile("s_barrier" ::: "memory");
    if (t + 2 < nt) STAGE((t + 2) * 64, t & 1);
  }

  float* out = outp + (long)bz * outBatch;
#pragma unroll
  for (int i = 0; i < 4; ++i) {
#pragma unroll
    for (int rr = 0; rr < 4; ++rr) {
      const int grow = m0 + wr * 64 + i * 16 + ((lane >> 4) << 2) + rr;
      float* orp = out + (long)grow * outRstride;
#pragma unroll
      for (int j = 0; j < 4; ++j) {
        const int col = n0 + wc * 64 + j * 16 + (lane & 15);
        orp[col] = acc[i][j][rr];
      }
    }
  }
}

// ---------------------------------------------------------------------------
// Scan (round-9/11 proven, verbatim): 512 threads/block, 4 cols/thread.
// asm prefetch depth 2 + counted vmcnt (3 VMEM/row -> ladder 1/3/5); one raw
// s_barrier per row; parity double-buffered LDS (m,s); exact wave max.
// ---------------------------------------------------------------------------
template <int VM>
static __device__ __forceinline__ void scan_row(
    float* __restrict__ attn, unsigned short* __restrict__ attnb,
    int b, int q, int lane, int wid, int s0,
    const bool* msk, float* acc, f32x4& buf, float2 (&red)[2][8]) {
  const float L2E = 1.4426950408889634f;

  if constexpr (VM == 1)      asm volatile("s_waitcnt vmcnt(1)" ::: "memory");
  else if constexpr (VM == 3) asm volatile("s_waitcnt vmcnt(3)" ::: "memory");
  else                        asm volatile("s_waitcnt vmcnt(5)" ::: "memory");
  __builtin_amdgcn_sched_barrier(0);

  float adj[4];
#pragma unroll
  for (int j = 0; j < 4; ++j)
    adj[j] = msk[j] ? -1e30f : (buf[j] - acc[j]);

  int pr = q + 2; if (pr > Q_ - 1) pr = Q_ - 1;
  const float* pp = attn + ((long)(pr * B_ + b)) * S_ + s0;
  asm volatile("global_load_dwordx4 %0, %1, off"
               : "=&v"(buf)
               : "v"(pp), "v"(adj[0]), "v"(adj[1]), "v"(adj[2]), "v"(adj[3])
               : "memory");

  float lm = fmaxf(fmaxf(adj[0], adj[1]), fmaxf(adj[2], adj[3]));
#pragma unroll
  for (int off = 32; off > 0; off >>= 1) lm = fmaxf(lm, __shfl_xor(lm, off));

  float e[4];
#pragma unroll
  for (int j = 0; j < 4; ++j) {
    const float x = exp2f((adj[j] - lm) * L2E);
    e[j] = msk[j] ? 0.f : x;
  }

  float ls = (e[0] + e[1]) + (e[2] + e[3]);
#pragma unroll
  for (int off = 32; off > 0; off >>= 1) ls += __shfl_xor(ls, off);

  const int p = q & 1;
  if (lane == 0) red[p][wid] = make_float2(lm, ls);
  asm volatile("s_waitcnt lgkmcnt(0)\n\ts_barrier" ::: "memory");

  const float2 v0 = red[p][0], v1 = red[p][1], v2 = red[p][2], v3 = red[p][3];
  const float2 v4 = red[p][4], v5 = red[p][5], v6 = red[p][6], v7 = red[p][7];
  const float M = fmaxf(fmaxf(fmaxf(v0.x, v1.x), fmaxf(v2.x, v3.x)),
                        fmaxf(fmaxf(v4.x, v5.x), fmaxf(v6.x, v7.x)));
  const float tot = v0.y * exp2f((v0.x - M) * L2E) + v1.y * exp2f((v1.x - M) * L2E) +
                    v2.y * exp2f((v2.x - M) * L2E) + v3.y * exp2f((v3.x - M) * L2E) +
                    v4.y * exp2f((v4.x - M) * L2E) + v5.y * exp2f((v5.x - M) * L2E) +
                    v6.y * exp2f((v6.x - M) * L2E) + v7.y * exp2f((v7.x - M) * L2E);
  const float scale = exp2f((lm - M) * L2E) / tot;

  f32x4 av;
#pragma unroll
  for (int j = 0; j < 4; ++j) {
    av[j] = e[j] * scale;
    acc[j] += av[j];
  }
  *(f32x4*)(attn + ((long)(q * B_ + b)) * S_ + s0) = av;
  uint2 pk;
  pk.x = (unsigned int)f2bf(av[0]) | ((unsigned int)f2bf(av[1]) << 16);
  pk.y = (unsigned int)f2bf(av[2]) | ((unsigned int)f2bf(av[3]) << 16);
  *(uint2*)(attnb + ((long)b * Q_ + q) * S_ + s0) = pk;
}

__global__ __launch_bounds__(512)
void scan_kernel(const int* __restrict__ mask, float* __restrict__ attn,
                 float* __restrict__ accum_out, unsigned short* __restrict__ attnb) {
  const int b = blockIdx.x;
  const int tid = threadIdx.x;
  const int lane = tid & 63;
  const int wid = tid >> 6;
  const int s0 = tid * 4;

  __shared__ float2 red[2][8];

  const int4 mk = *(const int4*)(mask + (long)b * S_ + s0);
  const bool msk[4] = {mk.x != 0, mk.y != 0, mk.z != 0, mk.w != 0};
  asm volatile("" :: "v"(mk.x), "v"(mk.y), "v"(mk.z), "v"(mk.w));

  float acc[4] = {0.f, 0.f, 0.f, 0.f};

  f32x4 bufE, bufO;
  const float* p0 = attn + (long)b * S_ + s0;
  asm volatile("global_load_dwordx4 %0, %1, off" : "=&v"(bufE) : "v"(p0) : "memory");
  const float* p1 = attn + ((long)(B_ + b)) * S_ + s0;
  asm volatile("global_load_dwordx4 %0, %1, off" : "=&v"(bufO) : "v"(p1) : "memory");

  scan_row<1>(attn, attnb, b, 0, lane, wid, s0, msk, acc, bufE, red);
  scan_row<3>(attn, attnb, b, 1, lane, wid, s0, msk, acc, bufO, red);
  for (int q = 2; q < Q_; q += 2) {
    scan_row<5>(attn, attnb, b, q,     lane, wid, s0, msk, acc, bufE, red);
    scan_row<5>(attn, attnb, b, q + 1, lane, wid, s0, msk, acc, bufO, red);
  }

  f32x4 a4;
#pragma unroll
  for (int j = 0; j < 4; ++j) a4[j] = acc[j];
  *(f32x4*)(accum_out + (long)b * S_ + s0) = a4;
}

extern "C" void kernel_launch(void* const* d_in, const int* in_sizes, int n_in,
                              void* d_out, int out_size, void* d_ws, size_t ws_size,
                              hipStream_t stream) {
  const float* ctx   = (const float*)d_in[0];  // [B,S,C] f32
  const float* query = (const float*)d_in[1];  // [Q,B,D] f32
  const int*   mask  = (const int*)d_in[2];    // [B,S] int32 (bool)
  const float* W     = (const float*)d_in[3];  // [C,D] f32

  float* out = (float*)d_out;
  float* attn = out;                                      // [Q,B,S]
  float* accum_out = out + (size_t)Q_ * B_ * S_;          // [B,1,S]
  float* comp = accum_out + (size_t)B_ * S_;              // [Q,B,C]

  char* ws = (char*)d_ws;
  float* qw = (float*)ws;                                                   // [B,Q,C] f32, 16 MiB
  unsigned short* ctxT  = (unsigned short*)(ws + (size_t)16 * 1024 * 1024); // [B,C,S] bf16, 128 MiB
  unsigned short* attnb = (unsigned short*)(ws + (size_t)16 * 1024 * 1024 +
                                            (size_t)B_ * C_ * S_ * 2);      // [B,Q,S] bf16, 16 MiB

  // 1) QW[b,q,c] = sum_d query[q,b,d] * W[c,d]  (3-pass split, pipelined DMA)
  gemm_f32<false><<<dim3(C_ / 128, (Q_ * B_) / 128, 1), 256, 65536, stream>>>(
      query, W, qw, D_, 0L, 0L, 0L, (long)D_, (long)D_, (long)C_, 1, nullptr, 0L);

  // 2) scores[q,b,s] = sum_c QW[b,q,c] * ctx[b,s,c]  + fused ctxT write-out
  gemm_f32<true><<<dim3(S_ / 128, 1, B_), 256, 65536, stream>>>(
      qw, ctx, attn, C_, (long)Q_ * C_, (long)S_ * C_, (long)S_,
      (long)C_, (long)C_, (long)B_ * S_, 0, ctxT, (long)S_);

  // 3) sequential coverage-softmax scan (in-place attention + accum + bf16 copy)
  scan_kernel<<<B_, 512, 0, stream>>>(mask, attn, accum_out, attnb);

  // 4) composition[q,b,c] = sum_s attnb[b,q,s] * ctxT[b,c,s]  (pipelined DMA)
  gemm_bf16<<<dim3(C_ / 128, 1, B_), 256, 65536, stream>>>(
      attnb, ctxT, comp, S_, (long)Q_ * S_, (long)C_ * S_, (long)C_,
      (long)S_, (long)S_, (long)B_ * C_);
}

// Round 20
// 319.825 us; speedup vs baseline: 1.2606x; 1.0571x over previous
//
#include <hip/hip_runtime.h>

#define B_ 32
#define Q_ 128
#define S_ 2048
#define C_ 1024
#define D_ 1024

typedef __attribute__((ext_vector_type(8))) short bf16x8;
typedef __attribute__((ext_vector_type(4))) float f32x4;
typedef __attribute__((ext_vector_type(4))) unsigned int u32x4;

static __device__ __forceinline__ unsigned short f2bf(float f) {
  unsigned int u = __float_as_uint(f);
  u = (u + 0x7FFFu + ((u >> 16) & 1u)) >> 16;
  return (unsigned short)u;
}
static __device__ __forceinline__ float bf2f(unsigned short h) {
  return __uint_as_float(((unsigned int)h) << 16);
}

// async 16B global->LDS (DMA; dest = wave-uniform base + lane*16)
static __device__ __forceinline__ void gl_lds16(const void* g, void* l) {
  __builtin_amdgcn_global_load_lds(
      (const __attribute__((address_space(1))) unsigned int*)g,
      (__attribute__((address_space(3))) unsigned int*)l, 16, 0, 0);
}

// DPP row-rotate (within 16-lane rows): VALU-speed cross-lane, no lgkm wait.
// row_ror:k ctrl = 0x120|k; all source lanes valid for ror (no 0-injection).
template <int CTRL>
static __device__ __forceinline__ float dpp_ror(float v) {
  return __uint_as_float((unsigned int)__builtin_amdgcn_update_dpp(
      0, (int)__float_as_uint(v), CTRL, 0xf, 0xf, false));
}

// TRUNCATION split of 8 f32 into hi/lo bf16x8 via v_perm_b32 packing
// (round-18 proven).
static __device__ __forceinline__ void split8(const f32x4 x0, const f32x4 x1,
                                              bf16x8& hi, bf16x8& lo) {
  u32x4 h, l;
#pragma unroll
  for (int p = 0; p < 2; ++p) {
    const unsigned int a0 = __float_as_uint(x0[2 * p]);
    const unsigned int a1 = __float_as_uint(x0[2 * p + 1]);
    h[p] = __builtin_amdgcn_perm(a1, a0, 0x07060302u);
    const float r0 = x0[2 * p]     - __uint_as_float(a0 & 0xffff0000u);
    const float r1 = x0[2 * p + 1] - __uint_as_float(a1 & 0xffff0000u);
    l[p] = __builtin_amdgcn_perm(__float_as_uint(r1), __float_as_uint(r0), 0x07060302u);
  }
#pragma unroll
  for (int p = 0; p < 2; ++p) {
    const unsigned int a0 = __float_as_uint(x1[2 * p]);
    const unsigned int a1 = __float_as_uint(x1[2 * p + 1]);
    h[2 + p] = __builtin_amdgcn_perm(a1, a0, 0x07060302u);
    const float r0 = x1[2 * p]     - __uint_as_float(a0 & 0xffff0000u);
    const float r1 = x1[2 * p + 1] - __uint_as_float(a1 & 0xffff0000u);
    l[2 + p] = __builtin_amdgcn_perm(__float_as_uint(r1), __float_as_uint(r0), 0x07060302u);
  }
  hi = __builtin_bit_cast(bf16x8, h);
  lo = __builtin_bit_cast(bf16x8, l);
}

// ---------------------------------------------------------------------------
// f32-input split GEMM (rounds 16-18 proven, verbatim): BK=32, 128x128 tile,
// double-buffered global_load_lds pipeline, counted vmcnt(8), raw barriers.
// FUSE: conflict-free bf16 transposed B-tile write-out (ctxT).
// ---------------------------------------------------------------------------
template <bool FUSE>
__global__ __launch_bounds__(256, 2)
void gemm_f32(const float* __restrict__ Aip, const float* __restrict__ Bip,
              float* __restrict__ outp, int K,
              long aBatch, long bBatch, long outBatch,
              long aRstride, long bRstride, long outRstride, int remapQB,
              unsigned short* __restrict__ fuseOut, long fuseRstride) {
  extern __shared__ char smem[];
  float* sA = (float*)smem;            // [2][4096] f32
  float* sB = sA + 8192;               // [2][4096] f32

  const int tid = threadIdx.x;
  const int lane = tid & 63;
  const int w = tid >> 6;              // wave 0..3
  const int wr = w >> 1;
  const int wc = w & 1;
  const int m0 = blockIdx.y * 128;
  const int n0 = blockIdx.x * 128;
  const int bz = blockIdx.z;
  const int frow = lane & 15;
  const int cc = lane >> 4;            // K-subchunk 0..3

  const float* Af = Aip + (long)bz * aBatch;
  const float* Bf = Bip + (long)bz * bBatch;

  f32x4 acc[4][4];
#pragma unroll
  for (int i = 0; i < 4; ++i)
#pragma unroll
    for (int j = 0; j < 4; ++j) acc[i][j] = (f32x4){0.f, 0.f, 0.f, 0.f};

  auto STAGE = [&](int ktt, int bufi) {
#pragma unroll
    for (int i = 0; i < 4; ++i) {
      const int rr = (w * 4 + i) * 8 + (lane >> 3);   // tile row 0..127
      const int cs = (lane & 7) ^ (rr & 7);           // pre-swizzled src chunk
      gl_lds16(Af + (long)(m0 + rr) * aRstride + ktt + cs * 4,
               sA + bufi * 4096 + (w * 4 + i) * 256);
    }
#pragma unroll
    for (int i = 0; i < 4; ++i) {
      const int rr = (w * 4 + i) * 8 + (lane >> 3);
      const int cs = (lane & 7) ^ (rr & 7);
      gl_lds16(Bf + (long)(n0 + rr) * bRstride + ktt + cs * 4,
               sB + bufi * 4096 + (w * 4 + i) * 256);
    }
  };

  const int nt = K >> 5;   // 32 steps at K=1024
  STAGE(0, 0);
  STAGE(32, 1);

  for (int t = 0; t < nt; ++t) {
    if (t + 1 < nt) { asm volatile("s_waitcnt vmcnt(8)" ::: "memory"); }
    else            { asm volatile("s_waitcnt vmcnt(0)" ::: "memory"); }
    __builtin_amdgcn_sched_barrier(0);
    asm volatile("s_barrier" ::: "memory");

    const float* sAb = sA + (t & 1) * 4096;
    const float* sBb = sB + (t & 1) * 4096;

    bf16x8 ah[4], al[4], bh[4], bl[4];
#pragma unroll
    for (int i = 0; i < 4; ++i) {
      const int row = wr * 64 + i * 16 + frow;
      const int c0 = ((cc * 2) ^ (row & 7)) << 2;
      const int c1 = ((cc * 2 + 1) ^ (row & 7)) << 2;
      split8(*(const f32x4*)(sAb + row * 32 + c0),
             *(const f32x4*)(sAb + row * 32 + c1), ah[i], al[i]);
    }
#pragma unroll
    for (int j = 0; j < 4; ++j) {
      const int row = wc * 64 + j * 16 + frow;
      const int c0 = ((cc * 2) ^ (row & 7)) << 2;
      const int c1 = ((cc * 2 + 1) ^ (row & 7)) << 2;
      split8(*(const f32x4*)(sBb + row * 32 + c0),
             *(const f32x4*)(sBb + row * 32 + c1), bh[j], bl[j]);
    }
#pragma unroll
    for (int i = 0; i < 4; ++i)
#pragma unroll
      for (int j = 0; j < 4; ++j) {
        acc[i][j] = __builtin_amdgcn_mfma_f32_16x16x32_bf16(ah[i], bh[j], acc[i][j], 0, 0, 0);
        acc[i][j] = __builtin_amdgcn_mfma_f32_16x16x32_bf16(ah[i], bl[j], acc[i][j], 0, 0, 0);
        acc[i][j] = __builtin_amdgcn_mfma_f32_16x16x32_bf16(al[i], bh[j], acc[i][j], 0, 0, 0);
      }

    if constexpr (FUSE) {
      const int k = lane & 31;
      const int nb = w * 32 + ((lane >> 5) << 4);
      unsigned short vals[16];
#pragma unroll
      for (int i = 0; i < 16; ++i) {
        const int row = nb + i;
        vals[i] = f2bf(sBb[row * 32 + (((k >> 2) ^ (row & 7)) << 2) + (k & 3)]);
      }
      unsigned short* dst = fuseOut + ((long)bz * K + t * 32 + k) * fuseRstride + n0 + nb;
      *(bf16x8*)(dst + 0) = *(const bf16x8*)(vals + 0);
      *(bf16x8*)(dst + 8) = *(const bf16x8*)(vals + 8);
    }

    asm volatile("s_barrier" ::: "memory");
    if (t + 2 < nt) STAGE((t + 2) * 32, t & 1);
  }

  float* out = outp + (long)bz * outBatch;
#pragma unroll
  for (int i = 0; i < 4; ++i) {
#pragma unroll
    for (int rr = 0; rr < 4; ++rr) {
      const int grow = m0 + wr * 64 + i * 16 + ((lane >> 4) << 2) + rr;
      const long orow = remapQB ? ((long)(grow & 31) * 128 + (grow >> 5)) : (long)grow;
      float* orp = out + orow * outRstride;
#pragma unroll
      for (int j = 0; j < 4; ++j) {
        const int col = n0 + wc * 64 + j * 16 + (lane & 15);
        orp[col] = acc[i][j][rr];
      }
    }
  }
}

// ---------------------------------------------------------------------------
// bf16 copy GEMM, pipelined (round-19 proven, verbatim): BK=64, 128x128 tile,
// DMA staging, double-buffered, counted vmcnt(8), raw barriers.
// ---------------------------------------------------------------------------
__global__ __launch_bounds__(256, 2)
void gemm_bf16(const unsigned short* __restrict__ Aip, const unsigned short* __restrict__ Bip,
               float* __restrict__ outp, int K,
               long aBatch, long bBatch, long outBatch,
               long aRstride, long bRstride, long outRstride) {
  extern __shared__ char smem[];
  unsigned short* sA = (unsigned short*)smem;   // [2][8192] bf16
  unsigned short* sB = sA + 16384;              // [2][8192] bf16

  const int tid = threadIdx.x;
  const int lane = tid & 63;
  const int w = tid >> 6;
  const int wr = w >> 1;
  const int wc = w & 1;
  const int m0 = blockIdx.y * 128;
  const int n0 = blockIdx.x * 128;
  const int bz = blockIdx.z;
  const int frow = lane & 15;
  const int cc = lane >> 4;   // 0..3

  const unsigned short* Ab = Aip + (long)bz * aBatch;
  const unsigned short* Bb = Bip + (long)bz * bBatch;

  f32x4 acc[4][4];
#pragma unroll
  for (int i = 0; i < 4; ++i)
#pragma unroll
    for (int j = 0; j < 4; ++j) acc[i][j] = (f32x4){0.f, 0.f, 0.f, 0.f};

  auto STAGE = [&](int ktt, int bufi) {
#pragma unroll
    for (int i = 0; i < 4; ++i) {
      const int rr = (w * 4 + i) * 8 + (lane >> 3);
      const int cs = (lane & 7) ^ (rr & 7);
      gl_lds16(Ab + (long)(m0 + rr) * aRstride + ktt + cs * 8,
               sA + bufi * 8192 + (w * 4 + i) * 512);
    }
#pragma unroll
    for (int i = 0; i < 4; ++i) {
      const int rr = (w * 4 + i) * 8 + (lane >> 3);
      const int cs = (lane & 7) ^ (rr & 7);
      gl_lds16(Bb + (long)(n0 + rr) * bRstride + ktt + cs * 8,
               sB + bufi * 8192 + (w * 4 + i) * 512);
    }
  };

  const int nt = K >> 6;   // 32 steps at K=2048
  STAGE(0, 0);
  STAGE(64, 1);

  for (int t = 0; t < nt; ++t) {
    if (t + 1 < nt) { asm volatile("s_waitcnt vmcnt(8)" ::: "memory"); }
    else            { asm volatile("s_waitcnt vmcnt(0)" ::: "memory"); }
    __builtin_amdgcn_sched_barrier(0);
    asm volatile("s_barrier" ::: "memory");

    const unsigned short* sAb = sA + (t & 1) * 8192;
    const unsigned short* sBb = sB + (t & 1) * 8192;

#pragma unroll
    for (int kk = 0; kk < 2; ++kk) {
      bf16x8 ah[4], bh[4];
#pragma unroll
      for (int i = 0; i < 4; ++i) {
        const int row = wr * 64 + i * 16 + frow;
        const int ch = kk * 4 + cc;
        ah[i] = *(const bf16x8*)((const char*)sAb + row * 128 + ((ch ^ (row & 7)) << 4));
      }
#pragma unroll
      for (int j = 0; j < 4; ++j) {
        const int row = wc * 64 + j * 16 + frow;
        const int ch = kk * 4 + cc;
        bh[j] = *(const bf16x8*)((const char*)sBb + row * 128 + ((ch ^ (row & 7)) << 4));
      }
#pragma unroll
      for (int i = 0; i < 4; ++i)
#pragma unroll
        for (int j = 0; j < 4; ++j)
          acc[i][j] = __builtin_amdgcn_mfma_f32_16x16x32_bf16(ah[i], bh[j], acc[i][j], 0, 0, 0);
    }

    asm volatile("s_barrier" ::: "memory");
    if (t + 2 < nt) STAGE((t + 2) * 64, t & 1);
  }

  float* out = outp + (long)bz * outBatch;
#pragma unroll
  for (int i = 0; i < 4; ++i) {
#pragma unroll
    for (int rr = 0; rr < 4; ++rr) {
      const int grow = m0 + wr * 64 + i * 16 + ((lane >> 4) << 2) + rr;
      float* orp = out + (long)grow * outRstride;
#pragma unroll
      for (int j = 0; j < 4; ++j) {
        const int col = n0 + wc * 64 + j * 16 + (lane & 15);
        orp[col] = acc[i][j][rr];
      }
    }
  }
}

// ---------------------------------------------------------------------------
// Scan: round-9/11 structure (asm prefetch depth 2, counted vmcnt 1/3/5, one
// raw s_barrier/row, parity LDS (m,s), exact wave max). THIS ROUND: the
// cross-lane reductions use DPP row_ror (1,2,4,8) at VALU speed for the
// within-16 steps; only offsets 16 and 32 remain ds-shuffles. Max is exact
// (order-independent); sum is merely reassociated.
// ---------------------------------------------------------------------------
template <int VM>
static __device__ __forceinline__ void scan_row(
    float* __restrict__ attn, unsigned short* __restrict__ attnb,
    int b, int q, int lane, int wid, int s0,
    const bool* msk, float* acc, f32x4& buf, float2 (&red)[2][8]) {
  const float L2E = 1.4426950408889634f;

  if constexpr (VM == 1)      asm volatile("s_waitcnt vmcnt(1)" ::: "memory");
  else if constexpr (VM == 3) asm volatile("s_waitcnt vmcnt(3)" ::: "memory");
  else                        asm volatile("s_waitcnt vmcnt(5)" ::: "memory");
  __builtin_amdgcn_sched_barrier(0);

  float adj[4];
#pragma unroll
  for (int j = 0; j < 4; ++j)
    adj[j] = msk[j] ? -1e30f : (buf[j] - acc[j]);

  int pr = q + 2; if (pr > Q_ - 1) pr = Q_ - 1;
  const float* pp = attn + ((long)(pr * B_ + b)) * S_ + s0;
  asm volatile("global_load_dwordx4 %0, %1, off"
               : "=&v"(buf)
               : "v"(pp), "v"(adj[0]), "v"(adj[1]), "v"(adj[2]), "v"(adj[3])
               : "memory");

  // exact wave max: lane tree + 4x DPP ror + 2 shuffles
  float lm = fmaxf(fmaxf(adj[0], adj[1]), fmaxf(adj[2], adj[3]));
  lm = fmaxf(lm, dpp_ror<0x121>(lm));
  lm = fmaxf(lm, dpp_ror<0x122>(lm));
  lm = fmaxf(lm, dpp_ror<0x124>(lm));
  lm = fmaxf(lm, dpp_ror<0x128>(lm));
  lm = fmaxf(lm, __shfl_xor(lm, 16));
  lm = fmaxf(lm, __shfl_xor(lm, 32));

  float e[4];
#pragma unroll
  for (int j = 0; j < 4; ++j) {
    const float x = exp2f((adj[j] - lm) * L2E);
    e[j] = msk[j] ? 0.f : x;
  }

  // wave sum: lane tree + 4x DPP ror + 2 shuffles
  float ls = (e[0] + e[1]) + (e[2] + e[3]);
  ls += dpp_ror<0x121>(ls);
  ls += dpp_ror<0x122>(ls);
  ls += dpp_ror<0x124>(ls);
  ls += dpp_ror<0x128>(ls);
  ls += __shfl_xor(ls, 16);
  ls += __shfl_xor(ls, 32);

  const int p = q & 1;
  if (lane == 0) red[p][wid] = make_float2(lm, ls);
  asm volatile("s_waitcnt lgkmcnt(0)\n\ts_barrier" ::: "memory");

  const float2 v0 = red[p][0], v1 = red[p][1], v2 = red[p][2], v3 = red[p][3];
  const float2 v4 = red[p][4], v5 = red[p][5], v6 = red[p][6], v7 = red[p][7];
  const float M = fmaxf(fmaxf(fmaxf(v0.x, v1.x), fmaxf(v2.x, v3.x)),
                        fmaxf(fmaxf(v4.x, v5.x), fmaxf(v6.x, v7.x)));
  const float tot = v0.y * exp2f((v0.x - M) * L2E) + v1.y * exp2f((v1.x - M) * L2E) +
                    v2.y * exp2f((v2.x - M) * L2E) + v3.y * exp2f((v3.x - M) * L2E) +
                    v4.y * exp2f((v4.x - M) * L2E) + v5.y * exp2f((v5.x - M) * L2E) +
                    v6.y * exp2f((v6.x - M) * L2E) + v7.y * exp2f((v7.x - M) * L2E);
  const float scale = exp2f((lm - M) * L2E) / tot;

  f32x4 av;
#pragma unroll
  for (int j = 0; j < 4; ++j) {
    av[j] = e[j] * scale;
    acc[j] += av[j];
  }
  *(f32x4*)(attn + ((long)(q * B_ + b)) * S_ + s0) = av;
  uint2 pk;
  pk.x = (unsigned int)f2bf(av[0]) | ((unsigned int)f2bf(av[1]) << 16);
  pk.y = (unsigned int)f2bf(av[2]) | ((unsigned int)f2bf(av[3]) << 16);
  *(uint2*)(attnb + ((long)b * Q_ + q) * S_ + s0) = pk;
}

__global__ __launch_bounds__(512)
void scan_kernel(const int* __restrict__ mask, float* __restrict__ attn,
                 float* __restrict__ accum_out, unsigned short* __restrict__ attnb) {
  const int b = blockIdx.x;
  const int tid = threadIdx.x;
  const int lane = tid & 63;
  const int wid = tid >> 6;
  const int s0 = tid * 4;

  __shared__ float2 red[2][8];

  const int4 mk = *(const int4*)(mask + (long)b * S_ + s0);
  const bool msk[4] = {mk.x != 0, mk.y != 0, mk.z != 0, mk.w != 0};
  asm volatile("" :: "v"(mk.x), "v"(mk.y), "v"(mk.z), "v"(mk.w));

  float acc[4] = {0.f, 0.f, 0.f, 0.f};

  f32x4 bufE, bufO;
  const float* p0 = attn + (long)b * S_ + s0;
  asm volatile("global_load_dwordx4 %0, %1, off" : "=&v"(bufE) : "v"(p0) : "memory");
  const float* p1 = attn + ((long)(B_ + b)) * S_ + s0;
  asm volatile("global_load_dwordx4 %0, %1, off" : "=&v"(bufO) : "v"(p1) : "memory");

  scan_row<1>(attn, attnb, b, 0, lane, wid, s0, msk, acc, bufE, red);
  scan_row<3>(attn, attnb, b, 1, lane, wid, s0, msk, acc, bufO, red);
  for (int q = 2; q < Q_; q += 2) {
    scan_row<5>(attn, attnb, b, q,     lane, wid, s0, msk, acc, bufE, red);
    scan_row<5>(attn, attnb, b, q + 1, lane, wid, s0, msk, acc, bufO, red);
  }

  f32x4 a4;
#pragma unroll
  for (int j = 0; j < 4; ++j) a4[j] = acc[j];
  *(f32x4*)(accum_out + (long)b * S_ + s0) = a4;
}

extern "C" void kernel_launch(void* const* d_in, const int* in_sizes, int n_in,
                              void* d_out, int out_size, void* d_ws, size_t ws_size,
                              hipStream_t stream) {
  const float* ctx   = (const float*)d_in[0];  // [B,S,C] f32
  const float* query = (const float*)d_in[1];  // [Q,B,D] f32
  const int*   mask  = (const int*)d_in[2];    // [B,S] int32 (bool)
  const float* W     = (const float*)d_in[3];  // [C,D] f32

  float* out = (float*)d_out;
  float* attn = out;                                      // [Q,B,S]
  float* accum_out = out + (size_t)Q_ * B_ * S_;          // [B,1,S]
  float* comp = accum_out + (size_t)B_ * S_;              // [Q,B,C]

  char* ws = (char*)d_ws;
  float* qw = (float*)ws;                                                   // [B,Q,C] f32, 16 MiB
  unsigned short* ctxT  = (unsigned short*)(ws + (size_t)16 * 1024 * 1024); // [B,C,S] bf16, 128 MiB
  unsigned short* attnb = (unsigned short*)(ws + (size_t)16 * 1024 * 1024 +
                                            (size_t)B_ * C_ * S_ * 2);      // [B,Q,S] bf16, 16 MiB

  // 1) QW[b,q,c] = sum_d query[q,b,d] * W[c,d]  (3-pass split, pipelined DMA)
  gemm_f32<false><<<dim3(C_ / 128, (Q_ * B_) / 128, 1), 256, 65536, stream>>>(
      query, W, qw, D_, 0L, 0L, 0L, (long)D_, (long)D_, (long)C_, 1, nullptr, 0L);

  // 2) scores[q,b,s] = sum_c QW[b,q,c] * ctx[b,s,c]  + fused ctxT write-out
  gemm_f32<true><<<dim3(S_ / 128, 1, B_), 256, 65536, stream>>>(
      qw, ctx, attn, C_, (long)Q_ * C_, (long)S_ * C_, (long)S_,
      (long)C_, (long)C_, (long)B_ * S_, 0, ctxT, (long)S_);

  // 3) sequential coverage-softmax scan (in-place attention + accum + bf16 copy)
  scan_kernel<<<B_, 512, 0, stream>>>(mask, attn, accum_out, attnb);

  // 4) composition[q,b,c] = sum_s attnb[b,q,s] * ctxT[b,c,s]  (pipelined DMA)
  gemm_bf16<<<dim3(C_ / 128, 1, B_), 256, 65536, stream>>>(
      attnb, ctxT, comp, S_, (long)Q_ * S_, (long)C_ * S_, (long)C_,
      (long)S_, (long)S_, (long)B_ * C_);
}

// Round 21
// 286.231 us; speedup vs baseline: 1.4085x; 1.1174x over previous
//
#include <hip/hip_runtime.h>

#define B_ 32
#define Q_ 128
#define S_ 2048
#define C_ 1024
#define D_ 1024

typedef __attribute__((ext_vector_type(8))) short bf16x8;
typedef __attribute__((ext_vector_type(4))) float f32x4;
typedef __attribute__((ext_vector_type(4))) unsigned int u32x4;

static __device__ __forceinline__ unsigned short f2bf(float f) {
  unsigned int u = __float_as_uint(f);
  u = (u + 0x7FFFu + ((u >> 16) & 1u)) >> 16;
  return (unsigned short)u;
}
static __device__ __forceinline__ float bf2f(unsigned short h) {
  return __uint_as_float(((unsigned int)h) << 16);
}

// async 16B global->LDS (DMA; dest = wave-uniform base + lane*16)
static __device__ __forceinline__ void gl_lds16(const void* g, void* l) {
  __builtin_amdgcn_global_load_lds(
      (const __attribute__((address_space(1))) unsigned int*)g,
      (__attribute__((address_space(3))) unsigned int*)l, 16, 0, 0);
}

// DPP row-rotate (within 16-lane rows): VALU-speed cross-lane, no lgkm wait.
template <int CTRL>
static __device__ __forceinline__ float dpp_ror(float v) {
  return __uint_as_float((unsigned int)__builtin_amdgcn_update_dpp(
      0, (int)__float_as_uint(v), CTRL, 0xf, 0xf, false));
}

// TRUNCATION split of 8 f32 into hi/lo bf16x8 via v_perm_b32 packing
// (round-18 proven).
static __device__ __forceinline__ void split8(const f32x4 x0, const f32x4 x1,
                                              bf16x8& hi, bf16x8& lo) {
  u32x4 h, l;
#pragma unroll
  for (int p = 0; p < 2; ++p) {
    const unsigned int a0 = __float_as_uint(x0[2 * p]);
    const unsigned int a1 = __float_as_uint(x0[2 * p + 1]);
    h[p] = __builtin_amdgcn_perm(a1, a0, 0x07060302u);
    const float r0 = x0[2 * p]     - __uint_as_float(a0 & 0xffff0000u);
    const float r1 = x0[2 * p + 1] - __uint_as_float(a1 & 0xffff0000u);
    l[p] = __builtin_amdgcn_perm(__float_as_uint(r1), __float_as_uint(r0), 0x07060302u);
  }
#pragma unroll
  for (int p = 0; p < 2; ++p) {
    const unsigned int a0 = __float_as_uint(x1[2 * p]);
    const unsigned int a1 = __float_as_uint(x1[2 * p + 1]);
    h[2 + p] = __builtin_amdgcn_perm(a1, a0, 0x07060302u);
    const float r0 = x1[2 * p]     - __uint_as_float(a0 & 0xffff0000u);
    const float r1 = x1[2 * p + 1] - __uint_as_float(a1 & 0xffff0000u);
    l[2 + p] = __builtin_amdgcn_perm(__float_as_uint(r1), __float_as_uint(r0), 0x07060302u);
  }
  hi = __builtin_bit_cast(bf16x8, h);
  lo = __builtin_bit_cast(bf16x8, l);
}

// ---------------------------------------------------------------------------
// f32-input split GEMM (rounds 16-18 proven, verbatim): BK=32, 128x128 tile,
// double-buffered global_load_lds pipeline, counted vmcnt(8), raw barriers.
// FUSE: conflict-free bf16 transposed B-tile write-out (ctxT).
// ---------------------------------------------------------------------------
template <bool FUSE>
__global__ __launch_bounds__(256, 2)
void gemm_f32(const float* __restrict__ Aip, const float* __restrict__ Bip,
              float* __restrict__ outp, int K,
              long aBatch, long bBatch, long outBatch,
              long aRstride, long bRstride, long outRstride, int remapQB,
              unsigned short* __restrict__ fuseOut, long fuseRstride) {
  extern __shared__ char smem[];
  float* sA = (float*)smem;            // [2][4096] f32
  float* sB = sA + 8192;               // [2][4096] f32

  const int tid = threadIdx.x;
  const int lane = tid & 63;
  const int w = tid >> 6;              // wave 0..3
  const int wr = w >> 1;
  const int wc = w & 1;
  const int m0 = blockIdx.y * 128;
  const int n0 = blockIdx.x * 128;
  const int bz = blockIdx.z;
  const int frow = lane & 15;
  const int cc = lane >> 4;            // K-subchunk 0..3

  const float* Af = Aip + (long)bz * aBatch;
  const float* Bf = Bip + (long)bz * bBatch;

  f32x4 acc[4][4];
#pragma unroll
  for (int i = 0; i < 4; ++i)
#pragma unroll
    for (int j = 0; j < 4; ++j) acc[i][j] = (f32x4){0.f, 0.f, 0.f, 0.f};

  auto STAGE = [&](int ktt, int bufi) {
#pragma unroll
    for (int i = 0; i < 4; ++i) {
      const int rr = (w * 4 + i) * 8 + (lane >> 3);   // tile row 0..127
      const int cs = (lane & 7) ^ (rr & 7);           // pre-swizzled src chunk
      gl_lds16(Af + (long)(m0 + rr) * aRstride + ktt + cs * 4,
               sA + bufi * 4096 + (w * 4 + i) * 256);
    }
#pragma unroll
    for (int i = 0; i < 4; ++i) {
      const int rr = (w * 4 + i) * 8 + (lane >> 3);
      const int cs = (lane & 7) ^ (rr & 7);
      gl_lds16(Bf + (long)(n0 + rr) * bRstride + ktt + cs * 4,
               sB + bufi * 4096 + (w * 4 + i) * 256);
    }
  };

  const int nt = K >> 5;   // 32 steps at K=1024
  STAGE(0, 0);
  STAGE(32, 1);

  for (int t = 0; t < nt; ++t) {
    if (t + 1 < nt) { asm volatile("s_waitcnt vmcnt(8)" ::: "memory"); }
    else            { asm volatile("s_waitcnt vmcnt(0)" ::: "memory"); }
    __builtin_amdgcn_sched_barrier(0);
    asm volatile("s_barrier" ::: "memory");

    const float* sAb = sA + (t & 1) * 4096;
    const float* sBb = sB + (t & 1) * 4096;

    bf16x8 ah[4], al[4], bh[4], bl[4];
#pragma unroll
    for (int i = 0; i < 4; ++i) {
      const int row = wr * 64 + i * 16 + frow;
      const int c0 = ((cc * 2) ^ (row & 7)) << 2;
      const int c1 = ((cc * 2 + 1) ^ (row & 7)) << 2;
      split8(*(const f32x4*)(sAb + row * 32 + c0),
             *(const f32x4*)(sAb + row * 32 + c1), ah[i], al[i]);
    }
#pragma unroll
    for (int j = 0; j < 4; ++j) {
      const int row = wc * 64 + j * 16 + frow;
      const int c0 = ((cc * 2) ^ (row & 7)) << 2;
      const int c1 = ((cc * 2 + 1) ^ (row & 7)) << 2;
      split8(*(const f32x4*)(sBb + row * 32 + c0),
             *(const f32x4*)(sBb + row * 32 + c1), bh[j], bl[j]);
    }
#pragma unroll
    for (int i = 0; i < 4; ++i)
#pragma unroll
      for (int j = 0; j < 4; ++j) {
        acc[i][j] = __builtin_amdgcn_mfma_f32_16x16x32_bf16(ah[i], bh[j], acc[i][j], 0, 0, 0);
        acc[i][j] = __builtin_amdgcn_mfma_f32_16x16x32_bf16(ah[i], bl[j], acc[i][j], 0, 0, 0);
        acc[i][j] = __builtin_amdgcn_mfma_f32_16x16x32_bf16(al[i], bh[j], acc[i][j], 0, 0, 0);
      }

    if constexpr (FUSE) {
      const int k = lane & 31;
      const int nb = w * 32 + ((lane >> 5) << 4);
      unsigned short vals[16];
#pragma unroll
      for (int i = 0; i < 16; ++i) {
        const int row = nb + i;
        vals[i] = f2bf(sBb[row * 32 + (((k >> 2) ^ (row & 7)) << 2) + (k & 3)]);
      }
      unsigned short* dst = fuseOut + ((long)bz * K + t * 32 + k) * fuseRstride + n0 + nb;
      *(bf16x8*)(dst + 0) = *(const bf16x8*)(vals + 0);
      *(bf16x8*)(dst + 8) = *(const bf16x8*)(vals + 8);
    }

    asm volatile("s_barrier" ::: "memory");
    if (t + 2 < nt) STAGE((t + 2) * 32, t & 1);
  }

  float* out = outp + (long)bz * outBatch;
#pragma unroll
  for (int i = 0; i < 4; ++i) {
#pragma unroll
    for (int rr = 0; rr < 4; ++rr) {
      const int grow = m0 + wr * 64 + i * 16 + ((lane >> 4) << 2) + rr;
      const long orow = remapQB ? ((long)(grow & 31) * 128 + (grow >> 5)) : (long)grow;
      float* orp = out + orow * outRstride;
#pragma unroll
      for (int j = 0; j < 4; ++j) {
        const int col = n0 + wc * 64 + j * 16 + (lane & 15);
        orp[col] = acc[i][j][rr];
      }
    }
  }
}

// ---------------------------------------------------------------------------
// bf16 copy GEMM, pipelined (round-19 proven, verbatim): BK=64, 128x128 tile,
// DMA staging, double-buffered, counted vmcnt(8), raw barriers.
// ---------------------------------------------------------------------------
__global__ __launch_bounds__(256, 2)
void gemm_bf16(const unsigned short* __restrict__ Aip, const unsigned short* __restrict__ Bip,
               float* __restrict__ outp, int K,
               long aBatch, long bBatch, long outBatch,
               long aRstride, long bRstride, long outRstride) {
  extern __shared__ char smem[];
  unsigned short* sA = (unsigned short*)smem;   // [2][8192] bf16
  unsigned short* sB = sA + 16384;              // [2][8192] bf16

  const int tid = threadIdx.x;
  const int lane = tid & 63;
  const int w = tid >> 6;
  const int wr = w >> 1;
  const int wc = w & 1;
  const int m0 = blockIdx.y * 128;
  const int n0 = blockIdx.x * 128;
  const int bz = blockIdx.z;
  const int frow = lane & 15;
  const int cc = lane >> 4;   // 0..3

  const unsigned short* Ab = Aip + (long)bz * aBatch;
  const unsigned short* Bb = Bip + (long)bz * bBatch;

  f32x4 acc[4][4];
#pragma unroll
  for (int i = 0; i < 4; ++i)
#pragma unroll
    for (int j = 0; j < 4; ++j) acc[i][j] = (f32x4){0.f, 0.f, 0.f, 0.f};

  auto STAGE = [&](int ktt, int bufi) {
#pragma unroll
    for (int i = 0; i < 4; ++i) {
      const int rr = (w * 4 + i) * 8 + (lane >> 3);
      const int cs = (lane & 7) ^ (rr & 7);
      gl_lds16(Ab + (long)(m0 + rr) * aRstride + ktt + cs * 8,
               sA + bufi * 8192 + (w * 4 + i) * 512);
    }
#pragma unroll
    for (int i = 0; i < 4; ++i) {
      const int rr = (w * 4 + i) * 8 + (lane >> 3);
      const int cs = (lane & 7) ^ (rr & 7);
      gl_lds16(Bb + (long)(n0 + rr) * bRstride + ktt + cs * 8,
               sB + bufi * 8192 + (w * 4 + i) * 512);
    }
  };

  const int nt = K >> 6;   // 32 steps at K=2048
  STAGE(0, 0);
  STAGE(64, 1);

  for (int t = 0; t < nt; ++t) {
    if (t + 1 < nt) { asm volatile("s_waitcnt vmcnt(8)" ::: "memory"); }
    else            { asm volatile("s_waitcnt vmcnt(0)" ::: "memory"); }
    __builtin_amdgcn_sched_barrier(0);
    asm volatile("s_barrier" ::: "memory");

    const unsigned short* sAb = sA + (t & 1) * 8192;
    const unsigned short* sBb = sB + (t & 1) * 8192;

#pragma unroll
    for (int kk = 0; kk < 2; ++kk) {
      bf16x8 ah[4], bh[4];
#pragma unroll
      for (int i = 0; i < 4; ++i) {
        const int row = wr * 64 + i * 16 + frow;
        const int ch = kk * 4 + cc;
        ah[i] = *(const bf16x8*)((const char*)sAb + row * 128 + ((ch ^ (row & 7)) << 4));
      }
#pragma unroll
      for (int j = 0; j < 4; ++j) {
        const int row = wc * 64 + j * 16 + frow;
        const int ch = kk * 4 + cc;
        bh[j] = *(const bf16x8*)((const char*)sBb + row * 128 + ((ch ^ (row & 7)) << 4));
      }
#pragma unroll
      for (int i = 0; i < 4; ++i)
#pragma unroll
        for (int j = 0; j < 4; ++j)
          acc[i][j] = __builtin_amdgcn_mfma_f32_16x16x32_bf16(ah[i], bh[j], acc[i][j], 0, 0, 0);
    }

    asm volatile("s_barrier" ::: "memory");
    if (t + 2 < nt) STAGE((t + 2) * 64, t & 1);
  }

  float* out = outp + (long)bz * outBatch;
#pragma unroll
  for (int i = 0; i < 4; ++i) {
#pragma unroll
    for (int rr = 0; rr < 4; ++rr) {
      const int grow = m0 + wr * 64 + i * 16 + ((lane >> 4) << 2) + rr;
      float* orp = out + (long)grow * outRstride;
#pragma unroll
      for (int j = 0; j < 4; ++j) {
        const int col = n0 + wc * 64 + j * 16 + (lane & 15);
        orp[col] = acc[i][j][rr];
      }
    }
  }
}

// ---------------------------------------------------------------------------
// Scan: PROVISIONAL-SHIFT pipeline (this round). During row q we also reduce
// Mprov(q+1) = max(score(q+1) - acc_q) from the prefetched next row. Since
// acc_{q+1} = acc_q + av(q), 0 <= av <= 1: Mprov >= true max (e <= 1) and
// Mprov - max <= 1 (sum >= exp(-1)). Softmax is shift-invariant -> EXACT.
// Unlike round 4/5's broken stale-max (used row q's max for independent row
// q+1 -> unbounded jump -> inf), this shift is bounded by construction.
// Per row: exp starts immediately (shift known); sum butterfly and next-row
// max butterfly are independent chains (ILP); combine = 8 plain adds (no
// exp2). One barrier/row; parity LDS float2 = (sum, provmax).
// vmcnt ladders (2 consume points): row0 <1,1>, row1 <3,3>, rows>=2 <5,3>.
// ---------------------------------------------------------------------------
template <int VMA, int VMB>
static __device__ __forceinline__ void scan_row(
    float* __restrict__ attn, unsigned short* __restrict__ attnb,
    int b, int q, int lane, int wid, int s0,
    const bool* msk, float* acc, f32x4& buf, const f32x4& bufNext,
    float& Mprov, float2 (&red)[2][8]) {
  const float L2E = 1.4426950408889634f;

  if constexpr (VMA == 1)      asm volatile("s_waitcnt vmcnt(1)" ::: "memory");
  else if constexpr (VMA == 3) asm volatile("s_waitcnt vmcnt(3)" ::: "memory");
  else                         asm volatile("s_waitcnt vmcnt(5)" ::: "memory");
  __builtin_amdgcn_sched_barrier(0);

  float adj[4];
#pragma unroll
  for (int j = 0; j < 4; ++j)
    adj[j] = msk[j] ? -1e30f : (buf[j] - acc[j]);

  // prefetch row q+2 into buf (dummy operands order adj-compute before reload)
  int pr = q + 2; if (pr > Q_ - 1) pr = Q_ - 1;
  const float* pp = attn + ((long)(pr * B_ + b)) * S_ + s0;
  asm volatile("global_load_dwordx4 %0, %1, off"
               : "=&v"(buf)
               : "v"(pp), "v"(adj[0]), "v"(adj[1]), "v"(adj[2]), "v"(adj[3])
               : "memory");

  // e with the precomputed block-global shift (no max wait)
  float e[4];
#pragma unroll
  for (int j = 0; j < 4; ++j) {
    const float x = exp2f((adj[j] - Mprov) * L2E);
    e[j] = msk[j] ? 0.f : x;
  }

  // wave sum butterfly (chain 1)
  float ls = (e[0] + e[1]) + (e[2] + e[3]);
  ls += dpp_ror<0x121>(ls);
  ls += dpp_ror<0x122>(ls);
  ls += dpp_ror<0x124>(ls);
  ls += dpp_ror<0x128>(ls);
  ls += __shfl_xor(ls, 16);
  ls += __shfl_xor(ls, 32);

  // provisional max for row q+1 (chain 2, independent -> ILP)
  if constexpr (VMB == 1) asm volatile("s_waitcnt vmcnt(1)" ::: "memory");
  else                    asm volatile("s_waitcnt vmcnt(3)" ::: "memory");
  __builtin_amdgcn_sched_barrier(0);
  float ap[4];
#pragma unroll
  for (int j = 0; j < 4; ++j)
    ap[j] = msk[j] ? -1e30f : (bufNext[j] - acc[j]);
  float lmp = fmaxf(fmaxf(ap[0], ap[1]), fmaxf(ap[2], ap[3]));
  lmp = fmaxf(lmp, dpp_ror<0x121>(lmp));
  lmp = fmaxf(lmp, dpp_ror<0x122>(lmp));
  lmp = fmaxf(lmp, dpp_ror<0x124>(lmp));
  lmp = fmaxf(lmp, dpp_ror<0x128>(lmp));
  lmp = fmaxf(lmp, __shfl_xor(lmp, 16));
  lmp = fmaxf(lmp, __shfl_xor(lmp, 32));

  const int p = q & 1;
  if (lane == 0) red[p][wid] = make_float2(ls, lmp);
  asm volatile("s_waitcnt lgkmcnt(0)\n\ts_barrier" ::: "memory");

  // combine: plain adds + max (NO exp2)
  const float2 v0 = red[p][0], v1 = red[p][1], v2 = red[p][2], v3 = red[p][3];
  const float2 v4 = red[p][4], v5 = red[p][5], v6 = red[p][6], v7 = red[p][7];
  const float tot = ((v0.x + v1.x) + (v2.x + v3.x)) + ((v4.x + v5.x) + (v6.x + v7.x));
  const float Mn = fmaxf(fmaxf(fmaxf(v0.y, v1.y), fmaxf(v2.y, v3.y)),
                         fmaxf(fmaxf(v4.y, v5.y), fmaxf(v6.y, v7.y)));
  const float scale = 1.0f / tot;  // tot >= exp(-1): never 0

  f32x4 av;
#pragma unroll
  for (int j = 0; j < 4; ++j) {
    av[j] = e[j] * scale;
    acc[j] += av[j];
  }
  *(f32x4*)(attn + ((long)(q * B_ + b)) * S_ + s0) = av;
  uint2 pk;
  pk.x = (unsigned int)f2bf(av[0]) | ((unsigned int)f2bf(av[1]) << 16);
  pk.y = (unsigned int)f2bf(av[2]) | ((unsigned int)f2bf(av[3]) << 16);
  *(uint2*)(attnb + ((long)b * Q_ + q) * S_ + s0) = pk;

  Mprov = Mn;
}

__global__ __launch_bounds__(512)
void scan_kernel(const int* __restrict__ mask, float* __restrict__ attn,
                 float* __restrict__ accum_out, unsigned short* __restrict__ attnb) {
  const int b = blockIdx.x;
  const int tid = threadIdx.x;
  const int lane = tid & 63;
  const int wid = tid >> 6;
  const int s0 = tid * 4;

  __shared__ float2 red[2][8];

  const int4 mk = *(const int4*)(mask + (long)b * S_ + s0);
  const bool msk[4] = {mk.x != 0, mk.y != 0, mk.z != 0, mk.w != 0};
  asm volatile("" :: "v"(mk.x), "v"(mk.y), "v"(mk.z), "v"(mk.w));

  float acc[4] = {0.f, 0.f, 0.f, 0.f};

  f32x4 bufE, bufO;
  const float* p0 = attn + (long)b * S_ + s0;
  asm volatile("global_load_dwordx4 %0, %1, off" : "=&v"(bufE) : "v"(p0) : "memory");
  const float* p1 = attn + ((long)(B_ + b)) * S_ + s0;
  asm volatile("global_load_dwordx4 %0, %1, off" : "=&v"(bufO) : "v"(p1) : "memory");

  // prologue: exact masked max of row 0 (acc = 0) -> Mprov(0)
  float Mprov;
  {
    asm volatile("s_waitcnt vmcnt(1)" ::: "memory");
    __builtin_amdgcn_sched_barrier(0);
    float a0[4];
#pragma unroll
    for (int j = 0; j < 4; ++j) a0[j] = msk[j] ? -1e30f : bufE[j];
    float lm = fmaxf(fmaxf(a0[0], a0[1]), fmaxf(a0[2], a0[3]));
    lm = fmaxf(lm, dpp_ror<0x121>(lm));
    lm = fmaxf(lm, dpp_ror<0x122>(lm));
    lm = fmaxf(lm, dpp_ror<0x124>(lm));
    lm = fmaxf(lm, dpp_ror<0x128>(lm));
    lm = fmaxf(lm, __shfl_xor(lm, 16));
    lm = fmaxf(lm, __shfl_xor(lm, 32));
    if (lane == 0) red[1][wid] = make_float2(0.f, lm);
    asm volatile("s_waitcnt lgkmcnt(0)\n\ts_barrier" ::: "memory");
    Mprov = red[1][0].y;
#pragma unroll
    for (int w2 = 1; w2 < 8; ++w2) Mprov = fmaxf(Mprov, red[1][w2].y);
  }

  scan_row<1, 1>(attn, attnb, b, 0, lane, wid, s0, msk, acc, bufE, bufO, Mprov, red);
  scan_row<3, 3>(attn, attnb, b, 1, lane, wid, s0, msk, acc, bufO, bufE, Mprov, red);
  for (int q = 2; q < Q_; q += 2) {
    scan_row<5, 3>(attn, attnb, b, q,     lane, wid, s0, msk, acc, bufE, bufO, Mprov, red);
    scan_row<5, 3>(attn, attnb, b, q + 1, lane, wid, s0, msk, acc, bufO, bufE, Mprov, red);
  }

  f32x4 a4;
#pragma unroll
  for (int j = 0; j < 4; ++j) a4[j] = acc[j];
  *(f32x4*)(accum_out + (long)b * S_ + s0) = a4;
}

extern "C" void kernel_launch(void* const* d_in, const int* in_sizes, int n_in,
                              void* d_out, int out_size, void* d_ws, size_t ws_size,
                              hipStream_t stream) {
  const float* ctx   = (const float*)d_in[0];  // [B,S,C] f32
  const float* query = (const float*)d_in[1];  // [Q,B,D] f32
  const int*   mask  = (const int*)d_in[2];    // [B,S] int32 (bool)
  const float* W     = (const float*)d_in[3];  // [C,D] f32

  float* out = (float*)d_out;
  float* attn = out;                                      // [Q,B,S]
  float* accum_out = out + (size_t)Q_ * B_ * S_;          // [B,1,S]
  float* comp = accum_out + (size_t)B_ * S_;              // [Q,B,C]

  char* ws = (char*)d_ws;
  float* qw = (float*)ws;                                                   // [B,Q,C] f32, 16 MiB
  unsigned short* ctxT  = (unsigned short*)(ws + (size_t)16 * 1024 * 1024); // [B,C,S] bf16, 128 MiB
  unsigned short* attnb = (unsigned short*)(ws + (size_t)16 * 1024 * 1024 +
                                            (size_t)B_ * C_ * S_ * 2);      // [B,Q,S] bf16, 16 MiB

  // 1) QW[b,q,c] = sum_d query[q,b,d] * W[c,d]  (3-pass split, pipelined DMA)
  gemm_f32<false><<<dim3(C_ / 128, (Q_ * B_) / 128, 1), 256, 65536, stream>>>(
      query, W, qw, D_, 0L, 0L, 0L, (long)D_, (long)D_, (long)C_, 1, nullptr, 0L);

  // 2) scores[q,b,s] = sum_c QW[b,q,c] * ctx[b,s,c]  + fused ctxT write-out
  gemm_f32<true><<<dim3(S_ / 128, 1, B_), 256, 65536, stream>>>(
      qw, ctx, attn, C_, (long)Q_ * C_, (long)S_ * C_, (long)S_,
      (long)C_, (long)C_, (long)B_ * S_, 0, ctxT, (long)S_);

  // 3) sequential coverage-softmax scan (in-place attention + accum + bf16 copy)
  scan_kernel<<<B_, 512, 0, stream>>>(mask, attn, accum_out, attnb);

  // 4) composition[q,b,c] = sum_s attnb[b,q,s] * ctxT[b,c,s]  (pipelined DMA)
  gemm_bf16<<<dim3(C_ / 128, 1, B_), 256, 65536, stream>>>(
      attnb, ctxT, comp, S_, (long)Q_ * S_, (long)C_ * S_, (long)C_,
      (long)S_, (long)S_, (long)B_ * C_);
}